// Round 10
// baseline (225.167 us; speedup 1.0000x reference)
//
#include <hip/hip_runtime.h>
#include <hip/hip_bf16.h>
#include <stdint.h>

typedef short s16x8 __attribute__((ext_vector_type(8)));
typedef float f32x4 __attribute__((ext_vector_type(4)));
typedef float f32x16 __attribute__((ext_vector_type(16)));

union FragU { uint4 u; s16x8 v; };

static __device__ __forceinline__ uint32_t pk2bf(float a, float b) {
  union { __hip_bfloat162 h; uint32_t u; } cv;
  cv.h = __float22bfloat162_rn(make_float2(a, b));
  return cv.u;
}

static __device__ __forceinline__ unsigned short f2bf(float f) {
  union { float f; uint32_t u; } x; x.f = f;
  uint32_t r = x.u + 0x7FFFu + ((x.u >> 16) & 1u);  // RNE
  return (unsigned short)(r >> 16);
}

static __device__ __forceinline__ void gl_lds16(const void* g, void* lds_wave_base) {
  __builtin_amdgcn_global_load_lds(
      (const __attribute__((address_space(1))) uint32_t*)(uintptr_t)g,
      (__attribute__((address_space(3))) uint32_t*)(uintptr_t)lds_wave_base, 16, 0, 0);
}

// ---------------- prep: 4x weight transpose (blocks 0-1023) + qkv fp32->bf16 cvt ----------
__global__ __launch_bounds__(256) void prep_kernel(const float* __restrict__ W0,
                                                   const float* __restrict__ W1,
                                                   const float* __restrict__ W2,
                                                   const float* __restrict__ W3,
                                                   unsigned short* __restrict__ T0,
                                                   unsigned short* __restrict__ T1,
                                                   unsigned short* __restrict__ T2,
                                                   unsigned short* __restrict__ T3,
                                                   const float* __restrict__ qs,
                                                   const float* __restrict__ ks,
                                                   const float* __restrict__ vs,
                                                   unsigned short* __restrict__ Qc,
                                                   unsigned short* __restrict__ Kc,
                                                   unsigned short* __restrict__ Vc) {
  __shared__ unsigned short tile[64][68];
  const int blk = blockIdx.x;
  const int t = threadIdx.x;
  if (blk < 1024) {
    const int z = blk >> 8;
    const float* W = (z == 0) ? W0 : (z == 1) ? W1 : (z == 2) ? W2 : W3;
    unsigned short* WT = (z == 0) ? T0 : (z == 1) ? T1 : (z == 2) ? T2 : T3;
    const int n0 = (blk & 15) * 64, k0 = ((blk >> 4) & 15) * 64;
    const int r = t >> 4, c4 = (t & 15) * 4;
#pragma unroll
    for (int i = 0; i < 4; ++i) {
      const int k = i * 16 + r;
      const float4 v = *(const float4*)&W[(k0 + k) * 1024 + n0 + c4];
      tile[k][c4 + 0] = f2bf(v.x);
      tile[k][c4 + 1] = f2bf(v.y);
      tile[k][c4 + 2] = f2bf(v.z);
      tile[k][c4 + 3] = f2bf(v.w);
    }
    __syncthreads();
#pragma unroll
    for (int i = 0; i < 4; ++i) {
      const int n = i * 16 + r;
      ushort4 o;
      o.x = tile[c4 + 0][n];
      o.y = tile[c4 + 1][n];
      o.z = tile[c4 + 2][n];
      o.w = tile[c4 + 3][n];
      *(ushort4*)&WT[(n0 + n) * 1024 + k0 + c4] = o;
    }
  } else {
    const int c = blk - 1024;  // 0..6143
    const int z = c >> 11, sub = c & 2047;
    const float* src = (z == 0) ? qs : (z == 1) ? ks : vs;
    unsigned short* dst = (z == 0) ? Qc : (z == 1) ? Kc : Vc;
    const size_t base = ((size_t)sub * 256 + t) * 8;
    const float4 f0 = *(const float4*)(src + base);
    const float4 f1 = *(const float4*)(src + base + 4);
    const uint4 o{pk2bf(f0.x, f0.y), pk2bf(f0.z, f0.w), pk2bf(f1.x, f1.y), pk2bf(f1.z, f1.w)};
    *(uint4*)(dst + base) = o;
  }
}

// legacy wt-only (fallback path when ws too small for cvt buffers)
__global__ __launch_bounds__(256) void wt4_kernel(const float* __restrict__ W0,
                                                  const float* __restrict__ W1,
                                                  const float* __restrict__ W2,
                                                  const float* __restrict__ W3,
                                                  unsigned short* __restrict__ T0,
                                                  unsigned short* __restrict__ T1,
                                                  unsigned short* __restrict__ T2,
                                                  unsigned short* __restrict__ T3) {
  __shared__ unsigned short tile[64][68];
  const int z = blockIdx.z;
  const float* W = (z == 0) ? W0 : (z == 1) ? W1 : (z == 2) ? W2 : W3;
  unsigned short* WT = (z == 0) ? T0 : (z == 1) ? T1 : (z == 2) ? T2 : T3;
  const int t = threadIdx.x;
  const int n0 = blockIdx.x * 64, k0 = blockIdx.y * 64;
  const int r = t >> 4, c4 = (t & 15) * 4;
#pragma unroll
  for (int i = 0; i < 4; ++i) {
    const int k = i * 16 + r;
    const float4 v = *(const float4*)&W[(k0 + k) * 1024 + n0 + c4];
    tile[k][c4 + 0] = f2bf(v.x);
    tile[k][c4 + 1] = f2bf(v.y);
    tile[k][c4 + 2] = f2bf(v.z);
    tile[k][c4 + 3] = f2bf(v.w);
  }
  __syncthreads();
#pragma unroll
  for (int i = 0; i < 4; ++i) {
    const int n = i * 16 + r;
    ushort4 o;
    o.x = tile[c4 + 0][n];
    o.y = tile[c4 + 1][n];
    o.z = tile[c4 + 2][n];
    o.w = tile[c4 + 3][n];
    *(ushort4*)&WT[(n0 + n) * 1024 + k0 + c4] = o;
  }
}

// ---------------- fused QKV GEMM, all-bf16, 3-buf counted-vmcnt pipeline ----------------
__global__ __launch_bounds__(256, 3) void qkv_gemm_bf16(const unsigned short* __restrict__ Aq,
                                                        const unsigned short* __restrict__ Ak,
                                                        const unsigned short* __restrict__ Av,
                                                        const unsigned short* __restrict__ Wq,
                                                        const unsigned short* __restrict__ Wk,
                                                        const unsigned short* __restrict__ Wv,
                                                        const float* __restrict__ bq,
                                                        const float* __restrict__ bk,
                                                        const float* __restrict__ bv,
                                                        unsigned short* __restrict__ Qb,
                                                        unsigned short* __restrict__ Kb,
                                                        unsigned short* __restrict__ Vt,
                                                        const float qscale) {
  __shared__ char AsB[3][8192];
  __shared__ char BsB[3][8192];
  const int t = threadIdx.x;
  const int z = blockIdx.z;
  const unsigned short* A = (z == 0) ? Aq : (z == 1) ? Ak : Av;
  const unsigned short* BT = (z == 0) ? Wq : (z == 1) ? Wk : Wv;
  const float* bias = (z == 0) ? bq : (z == 1) ? bk : bv;
  const float scale = (z == 0) ? qscale : 1.0f;

  const int lane = t & 63, w = t >> 6;
  const int g = lane >> 4, li = lane & 15;
  const int wr = (w >> 1) * 64, wc = (w & 1) * 64;
  const int lin = blockIdx.x + 8 * blockIdx.y;
  const int work = (lin & 7) * 32 + (lin >> 3);
  const int m0 = (work >> 3) * 128, n0 = (work & 7) * 128;

  const int r1 = t >> 2, c1 = (t & 3) ^ ((r1 >> 1) & 3);
  const int r2 = r1 + 64, c2 = (t & 3) ^ ((r2 >> 1) & 3);

  auto stage = [&](int kt, int buf) {
    const int k0 = kt * 32;
    gl_lds16(A + (size_t)(m0 + r1) * 1024 + k0 + c1 * 8, &AsB[buf][0] + (w << 10));
    gl_lds16(A + (size_t)(m0 + r2) * 1024 + k0 + c2 * 8, &AsB[buf][0] + 4096 + (w << 10));
    gl_lds16(BT + (size_t)(n0 + r1) * 1024 + k0 + c1 * 8, &BsB[buf][0] + (w << 10));
    gl_lds16(BT + (size_t)(n0 + r2) * 1024 + k0 + c2 * 8, &BsB[buf][0] + 4096 + (w << 10));
  };

  f32x4 acc[4][4] = {};
  stage(0, 0);
  stage(1, 1);
  asm volatile("s_waitcnt vmcnt(4)" ::: "memory");
  asm volatile("s_barrier" ::: "memory");

  int cur = 0;
  for (int kt = 0; kt < 32; ++kt) {
    if (kt < 30) {
      int nb = cur + 2; if (nb >= 3) nb -= 3;
      stage(kt + 2, nb);
    }
    const char* Ab = &AsB[cur][0];
    const char* Bb = &BsB[cur][0];
    FragU a[4], bf[4];
#pragma unroll
    for (int i = 0; i < 4; ++i) {
      const int ra = wr + i * 16 + li;
      a[i].u = *(const uint4*)(Ab + ra * 64 + ((g ^ ((ra >> 1) & 3)) << 4));
      const int rb = wc + i * 16 + li;
      bf[i].u = *(const uint4*)(Bb + rb * 64 + ((g ^ ((rb >> 1) & 3)) << 4));
    }
#pragma unroll
    for (int fm = 0; fm < 4; ++fm)
#pragma unroll
      for (int fn = 0; fn < 4; ++fn)
        acc[fm][fn] = __builtin_amdgcn_mfma_f32_16x16x32_bf16(a[fm].v, bf[fn].v, acc[fm][fn], 0, 0, 0);

    if (kt < 30) {
      asm volatile("s_waitcnt vmcnt(4)" ::: "memory");
    } else if (kt == 30) {
      asm volatile("s_waitcnt vmcnt(0)" ::: "memory");
    }
    if (kt < 31) asm volatile("s_barrier" ::: "memory");
    cur = (cur == 2) ? 0 : cur + 1;
  }

  unsigned short* OutN = (z == 0) ? Qb : Kb;
#pragma unroll
  for (int fn = 0; fn < 4; ++fn) {
    const int n = n0 + wc + fn * 16 + li;
    const float bv2 = bias[n];
#pragma unroll
    for (int fm = 0; fm < 4; ++fm) {
      const int mb = m0 + wr + fm * 16 + g * 4;
      const f32x4 v = acc[fm][fn];
      ushort4 pk;
      pk.x = f2bf((v[0] + bv2) * scale);
      pk.y = f2bf((v[1] + bv2) * scale);
      pk.z = f2bf((v[2] + bv2) * scale);
      pk.w = f2bf((v[3] + bv2) * scale);
      if (z == 2) {
        const int bb = mb >> 11, s = mb & 2047;
        *(ushort4*)&Vt[(size_t)(bb * 1024 + n) * 2048 + s] = pk;
      } else {
        unsigned short* o = OutN;
        o[(size_t)(mb + 0) * 1024 + n] = pk.x;
        o[(size_t)(mb + 1) * 1024 + n] = pk.y;
        o[(size_t)(mb + 2) * 1024 + n] = pk.z;
        o[(size_t)(mb + 3) * 1024 + n] = pk.w;
      }
    }
  }
}

// ---------------- fallback fused QKV GEMM (fp32 A reg-convert, 2-buf) -------------------
__global__ __launch_bounds__(256, 3) void qkv_gemm_f32(const float* __restrict__ Aq,
                                                       const float* __restrict__ Ak,
                                                       const float* __restrict__ Av,
                                                       const unsigned short* __restrict__ Wq,
                                                       const unsigned short* __restrict__ Wk,
                                                       const unsigned short* __restrict__ Wv,
                                                       const float* __restrict__ bq,
                                                       const float* __restrict__ bk,
                                                       const float* __restrict__ bv,
                                                       unsigned short* __restrict__ Qb,
                                                       unsigned short* __restrict__ Kb,
                                                       unsigned short* __restrict__ Vt,
                                                       const float qscale) {
  __shared__ unsigned short As[2][128 * 32];
  __shared__ unsigned short Bs[2][128 * 32];
  const int t = threadIdx.x;
  const int z = blockIdx.z;
  const float* A = (z == 0) ? Aq : (z == 1) ? Ak : Av;
  const unsigned short* BT = (z == 0) ? Wq : (z == 1) ? Wk : Wv;
  const float* bias = (z == 0) ? bq : (z == 1) ? bk : bv;
  const float scale = (z == 0) ? qscale : 1.0f;

  const int lane = t & 63, w = t >> 6;
  const int g = lane >> 4, li = lane & 15;
  const int wr = (w >> 1) * 64, wc = (w & 1) * 64;
  const int lin = blockIdx.x + 8 * blockIdx.y;
  const int work = (lin & 7) * 32 + (lin >> 3);
  const int m0 = (work >> 3) * 128, n0 = (work & 7) * 128;

  const int arow = t >> 1, ac0 = (t & 1) * 2, asw = (arow >> 1) & 3;
  const int br1 = t >> 2, bg1 = (t & 3) ^ ((br1 >> 1) & 3);
  const int br2 = br1 + 64, bg2 = (t & 3) ^ ((br2 >> 1) & 3);

  auto stageB = [&](int k0, int buf) {
    gl_lds16(BT + (size_t)(n0 + br1) * 1024 + k0 + bg1 * 8, (char*)&Bs[buf][0] + (w << 10));
    gl_lds16(BT + (size_t)(n0 + br2) * 1024 + k0 + bg2 * 8, (char*)&Bs[buf][0] + 4096 + (w << 10));
  };

  uint4 ar0, ar1;
  auto loadA = [&](int k0) {
    const float* ga = A + (size_t)(m0 + arow) * 1024 + k0 + ac0 * 8;
    const float4 f0 = *(const float4*)(ga + 0), f1 = *(const float4*)(ga + 4);
    const float4 f2 = *(const float4*)(ga + 8), f3 = *(const float4*)(ga + 12);
    ar0 = uint4{pk2bf(f0.x, f0.y), pk2bf(f0.z, f0.w), pk2bf(f1.x, f1.y), pk2bf(f1.z, f1.w)};
    ar1 = uint4{pk2bf(f2.x, f2.y), pk2bf(f2.z, f2.w), pk2bf(f3.x, f3.y), pk2bf(f3.z, f3.w)};
  };
  auto storeA = [&](int buf) {
    char* ab = (char*)&As[buf][0] + arow * 64;
    *(uint4*)(ab + ((ac0 ^ asw) << 4)) = ar0;
    *(uint4*)(ab + (((ac0 + 1) ^ asw) << 4)) = ar1;
  };

  f32x4 acc[4][4] = {};
  stageB(0, 0);
  loadA(0);
  storeA(0);
  __syncthreads();
  int cur = 0;
  for (int k0 = 0; k0 < 1024; k0 += 32) {
    const bool more = (k0 + 32) < 1024;
    if (more) {
      stageB(k0 + 32, cur ^ 1);
      loadA(k0 + 32);
    }
    const char* Ab = (const char*)&As[cur][0];
    const char* Bb = (const char*)&Bs[cur][0];
    FragU a[4], bf[4];
#pragma unroll
    for (int i = 0; i < 4; ++i) {
      const int rowa = wr + i * 16 + li;
      a[i].u = *(const uint4*)(Ab + rowa * 64 + (((g) ^ ((rowa >> 1) & 3)) << 4));
      const int rowb = wc + i * 16 + li;
      bf[i].u = *(const uint4*)(Bb + rowb * 64 + (((g) ^ ((rowb >> 1) & 3)) << 4));
    }
#pragma unroll
    for (int fm = 0; fm < 4; ++fm)
#pragma unroll
      for (int fn = 0; fn < 4; ++fn)
        acc[fm][fn] = __builtin_amdgcn_mfma_f32_16x16x32_bf16(a[fm].v, bf[fn].v, acc[fm][fn], 0, 0, 0);
    if (more) storeA(cur ^ 1);
    __syncthreads();
    cur ^= 1;
  }

  unsigned short* OutN = (z == 0) ? Qb : Kb;
#pragma unroll
  for (int fn = 0; fn < 4; ++fn) {
    const int n = n0 + wc + fn * 16 + li;
    const float bv2 = bias[n];
#pragma unroll
    for (int fm = 0; fm < 4; ++fm) {
      const int mb = m0 + wr + fm * 16 + g * 4;
      const f32x4 v = acc[fm][fn];
      ushort4 pk;
      pk.x = f2bf((v[0] + bv2) * scale);
      pk.y = f2bf((v[1] + bv2) * scale);
      pk.z = f2bf((v[2] + bv2) * scale);
      pk.w = f2bf((v[3] + bv2) * scale);
      if (z == 2) {
        const int bb = mb >> 11, s = mb & 2047;
        *(ushort4*)&Vt[(size_t)(bb * 1024 + n) * 2048 + s] = pk;
      } else {
        unsigned short* o = OutN;
        o[(size_t)(mb + 0) * 1024 + n] = pk.x;
        o[(size_t)(mb + 1) * 1024 + n] = pk.y;
        o[(size_t)(mb + 2) * 1024 + n] = pk.z;
        o[(size_t)(mb + 3) * 1024 + n] = pk.w;
      }
    }
  }
}

// ---------------- out GEMM: fp32 out = ctx(bf16) @ WoT^T + bo (3-buf counted vmcnt) -----
__global__ __launch_bounds__(256, 3) void out_gemm(const unsigned short* __restrict__ A,
                                                   const unsigned short* __restrict__ BT,
                                                   const float* __restrict__ bias,
                                                   float* __restrict__ Out) {
  __shared__ char AsB[3][8192];
  __shared__ char BsB[3][8192];
  const int t = threadIdx.x;
  const int lane = t & 63, w = t >> 6;
  const int g = lane >> 4, li = lane & 15;
  const int wr = (w >> 1) * 64, wc = (w & 1) * 64;
  const int lin = blockIdx.x + 8 * blockIdx.y;
  const int work = (lin & 7) * 32 + (lin >> 3);
  const int m0 = (work >> 3) * 128, n0 = (work & 7) * 128;

  const int r1 = t >> 2, c1 = (t & 3) ^ ((r1 >> 1) & 3);
  const int r2 = r1 + 64, c2 = (t & 3) ^ ((r2 >> 1) & 3);

  auto stage = [&](int kt, int buf) {
    const int k0 = kt * 32;
    gl_lds16(A + (size_t)(m0 + r1) * 1024 + k0 + c1 * 8, &AsB[buf][0] + (w << 10));
    gl_lds16(A + (size_t)(m0 + r2) * 1024 + k0 + c2 * 8, &AsB[buf][0] + 4096 + (w << 10));
    gl_lds16(BT + (size_t)(n0 + r1) * 1024 + k0 + c1 * 8, &BsB[buf][0] + (w << 10));
    gl_lds16(BT + (size_t)(n0 + r2) * 1024 + k0 + c2 * 8, &BsB[buf][0] + 4096 + (w << 10));
  };

  f32x4 acc[4][4] = {};
  stage(0, 0);
  stage(1, 1);
  asm volatile("s_waitcnt vmcnt(4)" ::: "memory");
  asm volatile("s_barrier" ::: "memory");

  int cur = 0;
  for (int kt = 0; kt < 32; ++kt) {
    if (kt < 30) {
      int nb = cur + 2; if (nb >= 3) nb -= 3;
      stage(kt + 2, nb);
    }
    const char* Ab = &AsB[cur][0];
    const char* Bb = &BsB[cur][0];
    FragU a[4], bf[4];
#pragma unroll
    for (int i = 0; i < 4; ++i) {
      const int ra = wr + i * 16 + li;
      a[i].u = *(const uint4*)(Ab + ra * 64 + ((g ^ ((ra >> 1) & 3)) << 4));
      const int rb = wc + i * 16 + li;
      bf[i].u = *(const uint4*)(Bb + rb * 64 + ((g ^ ((rb >> 1) & 3)) << 4));
    }
#pragma unroll
    for (int fm = 0; fm < 4; ++fm)
#pragma unroll
      for (int fn = 0; fn < 4; ++fn)
        acc[fm][fn] = __builtin_amdgcn_mfma_f32_16x16x32_bf16(a[fm].v, bf[fn].v, acc[fm][fn], 0, 0, 0);

    if (kt < 30) {
      asm volatile("s_waitcnt vmcnt(4)" ::: "memory");
    } else if (kt == 30) {
      asm volatile("s_waitcnt vmcnt(0)" ::: "memory");
    }
    if (kt < 31) asm volatile("s_barrier" ::: "memory");
    cur = (cur == 2) ? 0 : cur + 1;
  }

#pragma unroll
  for (int fn = 0; fn < 4; ++fn) {
    const int n = n0 + wc + fn * 16 + li;
    const float bv = bias[n];
#pragma unroll
    for (int fm = 0; fm < 4; ++fm) {
      const int mb = m0 + wr + fm * 16 + g * 4;
      const f32x4 v = acc[fm][fn];
#pragma unroll
      for (int r = 0; r < 4; ++r) Out[(size_t)(mb + r) * 1024 + n] = v[r] + bv;
    }
  }
}

// ---------------- flash attention, kv-parity split ----------------
// 1024 blocks (XCD-swizzled), 4 waves: wave (w) = q-sub (w>>1)*32, kv-parity w&1.
// Each wave: 16 KV tiles of its parity; pairs (2k, 2k+1) combine (m,l,O) via LDS at end.
// Single-buffer 32KB LDS (both parity tiles resident); raw s_barrier + lgkmcnt only so
// K/V register prefetch stays in flight across barriers. Swapped 32x32 MFMA structure.
__global__ __launch_bounds__(256, 4) void attn_kernel(const unsigned short* __restrict__ Qb,
                                                      const unsigned short* __restrict__ Kb,
                                                      const unsigned short* __restrict__ Vt,
                                                      const int* __restrict__ mask,
                                                      unsigned short* __restrict__ ctx) {
  __shared__ char smem[32768];  // Ks[2]:0..16K (per-parity 8K), Vs[2]:16K..32K
  const int t = threadIdx.x, lane = t & 63, w = t >> 6;
  const int l31 = lane & 31, hi = lane >> 5;
  const int p = w & 1;
  const int d0 = blockIdx.x;
  const int work = (d0 & 7) * 128 + (d0 >> 3);
  const int qblk = work & 31, bh = work >> 5;
  const int b = bh >> 4, h = bh & 15;
  const int qrow = b * 2048 + qblk * 64 + (w >> 1) * 32 + l31;

  const int srow = t >> 3, sch = t & 7;
  char* Ksp = smem + p * 8192;
  char* Vsp = smem + 16384 + p * 8192;

  const unsigned short* Kbase = Kb + (size_t)(b * 2048) * 1024 + h * 64;
  const unsigned short* Vbase = Vt + (size_t)(b * 1024 + h * 64) * 2048;

  uint4 kre0, kre1, kro0, kro1, vre0, vre1, vro0, vro1;
  int mv_next;
  auto loadK = [&](int i) {
    const int ke = (2 * i) * 64, ko = ke + 64;
    kre0 = *(const uint4*)(Kbase + (size_t)(ke + srow) * 1024 + sch * 8);
    kre1 = *(const uint4*)(Kbase + (size_t)(ke + srow + 32) * 1024 + sch * 8);
    kro0 = *(const uint4*)(Kbase + (size_t)(ko + srow) * 1024 + sch * 8);
    kro1 = *(const uint4*)(Kbase + (size_t)(ko + srow + 32) * 1024 + sch * 8);
    mv_next = mask[b * 2048 + (2 * i + p) * 64 + lane];
  };
  auto loadV = [&](int i) {
    const int ke = (2 * i) * 64, ko = ke + 64;
    vre0 = *(const uint4*)(Vbase + (size_t)srow * 2048 + ke + sch * 8);
    vre1 = *(const uint4*)(Vbase + (size_t)(srow + 32) * 2048 + ke + sch * 8);
    vro0 = *(const uint4*)(Vbase + (size_t)srow * 2048 + ko + sch * 8);
    vro1 = *(const uint4*)(Vbase + (size_t)(srow + 32) * 2048 + ko + sch * 8);
  };
  auto storeKV = [&]() {
    const int o0 = srow * 128 + ((sch * 16) ^ ((srow & 7) << 4));
    const int o1 = (srow + 32) * 128 + ((sch * 16) ^ ((srow & 7) << 4));
    char* k0 = smem;          char* k1 = smem + 8192;
    char* v0 = smem + 16384;  char* v1 = smem + 24576;
    *(uint4*)(k0 + o0) = kre0; *(uint4*)(k0 + o1) = kre1;
    *(uint4*)(k1 + o0) = kro0; *(uint4*)(k1 + o1) = kro1;
    *(uint4*)(v0 + o0) = vre0; *(uint4*)(v0 + o1) = vre1;
    *(uint4*)(v1 + o0) = vro0; *(uint4*)(v1 + o1) = vro1;
  };

  FragU qf[4];
  {
    const unsigned short* qb = Qb + (size_t)qrow * 1024 + h * 64 + hi * 8;
#pragma unroll
    for (int dc = 0; dc < 4; ++dc) qf[dc].u = *(const uint4*)(qb + dc * 16);
  }

  loadK(0);
  loadV(0);
  storeKV();
  int mv_cur = mv_next;
  asm volatile("s_waitcnt lgkmcnt(0)" ::: "memory");
  __builtin_amdgcn_s_barrier();
  loadK(1);

  f32x16 acc[2] = {};
  float m_run = 8.0f, l_run = 0.f;

  for (int i = 0; i < 16; ++i) {
    const int mvcur = mv_cur;

    // QK^T from Ks[p]
    f32x16 sc[2] = {};
    {
      __builtin_amdgcn_s_setprio(1);
#pragma unroll
      for (int t2 = 0; t2 < 2; ++t2) {
        const int row = t2 * 32 + l31;
        const int sw = (row & 7) << 4;
        const int rb = row * 128;
#pragma unroll
        for (int dc = 0; dc < 4; ++dc) {
          FragU kf;
          kf.u = *(const uint4*)(Ksp + rb + ((16 * (dc * 2 + hi)) ^ sw));
          sc[t2] = __builtin_amdgcn_mfma_f32_32x32x16_bf16(kf.v, qf[dc].v, sc[t2], 0, 0, 0);
        }
      }
      __builtin_amdgcn_s_setprio(0);
    }

    if (!__all(mvcur != 0)) {
#pragma unroll
      for (int t2 = 0; t2 < 2; ++t2)
#pragma unroll
        for (int r = 0; r < 16; ++r) {
          const int kvv = t2 * 32 + (r & 3) + 8 * (r >> 2) + 4 * hi;
          sc[t2][r] += (__shfl(mvcur, kvv, 64) ? 0.f : -30000.f);
        }
    }

    float pm = sc[0][0];
#pragma unroll
    for (int t2 = 0; t2 < 2; ++t2)
#pragma unroll
      for (int r = 0; r < 16; ++r) pm = fmaxf(pm, sc[t2][r]);
    pm = fmaxf(pm, __shfl_xor(pm, 32, 64));

    if (!__all(pm <= m_run + 8.f)) {
      const float m_new = fmaxf(m_run, pm);
      const float rsc = __builtin_amdgcn_exp2f(m_run - m_new);
      m_run = m_new;
      l_run *= rsc;
#pragma unroll
      for (int dt = 0; dt < 2; ++dt)
#pragma unroll
        for (int r = 0; r < 16; ++r) acc[dt][r] *= rsc;
    }

    if (i < 15) loadV(i + 1);  // V prefetch: hidden under exp+pack+PV

    float rs = 0.f;
#pragma unroll
    for (int t2 = 0; t2 < 2; ++t2)
#pragma unroll
      for (int r = 0; r < 16; ++r) {
        const float e = __builtin_amdgcn_exp2f(sc[t2][r] - m_run);
        sc[t2][r] = e;
        rs += e;
      }
    l_run += rs;

    FragU pf[4];
#pragma unroll
    for (int ks = 0; ks < 4; ++ks) {
      const int t2 = ks >> 1, s8 = (ks & 1) * 8;
      uint32_t U = pk2bf(sc[t2][s8 + 0], sc[t2][s8 + 1]);
      uint32_t V2 = pk2bf(sc[t2][s8 + 2], sc[t2][s8 + 3]);
      uint32_t X = pk2bf(sc[t2][s8 + 4], sc[t2][s8 + 5]);
      uint32_t Y = pk2bf(sc[t2][s8 + 6], sc[t2][s8 + 7]);
      asm("v_permlane32_swap_b32 %0, %1" : "+v"(U), "+v"(X));
      asm("v_permlane32_swap_b32 %0, %1" : "+v"(V2), "+v"(Y));
      pf[ks].u = uint4{U, V2, X, Y};
    }

    // PV from Vs[p]
    {
      __builtin_amdgcn_s_setprio(1);
#pragma unroll
      for (int dt = 0; dt < 2; ++dt) {
        const int drow = dt * 32 + l31;
        const int sw = (drow & 7) << 4;
        const int rb = drow * 128;
#pragma unroll
        for (int ks = 0; ks < 4; ++ks) {
          FragU vf;
          vf.u = *(const uint4*)(Vsp + rb + ((16 * (ks * 2 + hi)) ^ sw));
          acc[dt] = __builtin_amdgcn_mfma_f32_32x32x16_bf16(vf.v, pf[ks].v, acc[dt], 0, 0, 0);
        }
      }
      __builtin_amdgcn_s_setprio(0);
    }

    if (i < 15) {
      __builtin_amdgcn_s_barrier();  // all waves done reading iter-i LDS
      storeKV();                     // regs(i+1) -> LDS (vmcnt waits via data deps)
      mv_cur = mv_next;
      asm volatile("s_waitcnt lgkmcnt(0)" ::: "memory");
      __builtin_amdgcn_s_barrier();
      if (i < 14) loadK(i + 2);
    }
  }

  // ---- pair combine: waves (2k, 2k+1) share q rows; merge online-softmax states ----
  __builtin_amdgcn_s_barrier();
  float* exch = (float*)smem;
  float* myex = exch + (w >> 1) * (64 * 37) + lane * 37;
  if (p) {
    const float l_red = l_run + __shfl_xor(l_run, 32, 64);
#pragma unroll
    for (int dt = 0; dt < 2; ++dt)
#pragma unroll
      for (int r = 0; r < 16; ++r) myex[dt * 16 + r] = acc[dt][r];
    myex[32] = m_run;
    myex[33] = l_red;
  }
  asm volatile("s_waitcnt lgkmcnt(0)" ::: "memory");
  __builtin_amdgcn_s_barrier();
  if (!p) {
    const float m_b = myex[32], l_b = myex[33];
    const float l_a = l_run + __shfl_xor(l_run, 32, 64);
    const float m = fmaxf(m_run, m_b);
    const float ea = __builtin_amdgcn_exp2f(m_run - m);
    const float eb = __builtin_amdgcn_exp2f(m_b - m);
    const float inv_l = 1.0f / (l_a * ea + l_b * eb);
    unsigned short* cb = ctx + (size_t)qrow * 1024 + h * 64;
#pragma unroll
    for (int dt = 0; dt < 2; ++dt)
#pragma unroll
      for (int rq = 0; rq < 4; ++rq) {
        float v0 = (acc[dt][rq * 4 + 0] * ea + myex[dt * 16 + rq * 4 + 0] * eb) * inv_l;
        float v1 = (acc[dt][rq * 4 + 1] * ea + myex[dt * 16 + rq * 4 + 1] * eb) * inv_l;
        float v2 = (acc[dt][rq * 4 + 2] * ea + myex[dt * 16 + rq * 4 + 2] * eb) * inv_l;
        float v3 = (acc[dt][rq * 4 + 3] * ea + myex[dt * 16 + rq * 4 + 3] * eb) * inv_l;
        uint2 o;
        o.x = pk2bf(v0, v1);
        o.y = pk2bf(v2, v3);
        *(uint2*)(cb + dt * 32 + rq * 8 + hi * 4) = o;
      }
  }
}

extern "C" void kernel_launch(void* const* d_in, const int* in_sizes, int n_in,
                              void* d_out, int out_size, void* d_ws, size_t ws_size,
                              hipStream_t stream) {
  const float* query = (const float*)d_in[0];
  const float* key = (const float*)d_in[1];
  const float* value = (const float*)d_in[2];
  const int* mask = (const int*)d_in[3];
  const float* Wq = (const float*)d_in[4];
  const float* bq = (const float*)d_in[5];
  const float* Wk = (const float*)d_in[6];
  const float* bk = (const float*)d_in[7];
  const float* Wv = (const float*)d_in[8];
  const float* bv = (const float*)d_in[9];
  const float* Wo = (const float*)d_in[10];
  const float* bo = (const float*)d_in[11];
  float* out = (float*)d_out;

  const size_t MB = 1024 * 1024;
  if (ws_size < 40 * MB) return;
  char* ws = (char*)d_ws;
  unsigned short* WqT = (unsigned short*)(ws);
  unsigned short* WkT = (unsigned short*)(ws + 2 * MB);
  unsigned short* WvT = (unsigned short*)(ws + 4 * MB);
  unsigned short* WoT = (unsigned short*)(ws + 6 * MB);
  unsigned short* Qb = (unsigned short*)(ws + 8 * MB);
  unsigned short* Kb = (unsigned short*)(ws + 16 * MB);
  unsigned short* Vt = (unsigned short*)(ws + 24 * MB);
  unsigned short* ctx = (unsigned short*)(ws + 32 * MB);

  const dim3 tb(256);
  const float qscale = 0.125f * 1.4426950408889634f;

  if (ws_size >= 64 * MB) {
    unsigned short* Qc = (unsigned short*)(ws + 40 * MB);
    unsigned short* Kc = (unsigned short*)(ws + 48 * MB);
    unsigned short* Vc = (unsigned short*)(ws + 56 * MB);
    prep_kernel<<<dim3(7168), tb, 0, stream>>>(Wq, Wk, Wv, Wo, WqT, WkT, WvT, WoT,
                                               query, key, value, Qc, Kc, Vc);
    qkv_gemm_bf16<<<dim3(8, 32, 3), tb, 0, stream>>>(Qc, Kc, Vc, WqT, WkT, WvT,
                                                     bq, bk, bv, Qb, Kb, Vt, qscale);
  } else {
    wt4_kernel<<<dim3(16, 16, 4), tb, 0, stream>>>(Wq, Wk, Wv, Wo, WqT, WkT, WvT, WoT);
    qkv_gemm_f32<<<dim3(8, 32, 3), tb, 0, stream>>>(query, key, value, WqT, WkT, WvT,
                                                    bq, bk, bv, Qb, Kb, Vt, qscale);
  }

  attn_kernel<<<dim3(1024), tb, 0, stream>>>(Qb, Kb, Vt, mask, ctx);

  out_gemm<<<dim3(8, 32), tb, 0, stream>>>(ctx, WoT, bo, out);
}

// Round 11
// 130.361 us; speedup vs baseline: 1.7273x; 1.7273x over previous
//
#include <hip/hip_runtime.h>
#include <hip/hip_bf16.h>
#include <stdint.h>

typedef short s16x8 __attribute__((ext_vector_type(8)));
typedef float f32x4 __attribute__((ext_vector_type(4)));
typedef float f32x16 __attribute__((ext_vector_type(16)));

union FragU { uint4 u; s16x8 v; };

static __device__ __forceinline__ uint32_t pk2bf(float a, float b) {
  union { __hip_bfloat162 h; uint32_t u; } cv;
  cv.h = __float22bfloat162_rn(make_float2(a, b));
  return cv.u;
}

static __device__ __forceinline__ unsigned short f2bf(float f) {
  union { float f; uint32_t u; } x; x.f = f;
  uint32_t r = x.u + 0x7FFFu + ((x.u >> 16) & 1u);  // RNE
  return (unsigned short)(r >> 16);
}

static __device__ __forceinline__ void gl_lds16(const void* g, void* lds_wave_base) {
  __builtin_amdgcn_global_load_lds(
      (const __attribute__((address_space(1))) uint32_t*)(uintptr_t)g,
      (__attribute__((address_space(3))) uint32_t*)(uintptr_t)lds_wave_base, 16, 0, 0);
}

// ---------------- prep: 4x weight transpose (blocks 0-1023) + qkv fp32->bf16 cvt ----------
__global__ __launch_bounds__(256) void prep_kernel(const float* __restrict__ W0,
                                                   const float* __restrict__ W1,
                                                   const float* __restrict__ W2,
                                                   const float* __restrict__ W3,
                                                   unsigned short* __restrict__ T0,
                                                   unsigned short* __restrict__ T1,
                                                   unsigned short* __restrict__ T2,
                                                   unsigned short* __restrict__ T3,
                                                   const float* __restrict__ qs,
                                                   const float* __restrict__ ks,
                                                   const float* __restrict__ vs,
                                                   unsigned short* __restrict__ Qc,
                                                   unsigned short* __restrict__ Kc,
                                                   unsigned short* __restrict__ Vc) {
  __shared__ unsigned short tile[64][68];
  const int blk = blockIdx.x;
  const int t = threadIdx.x;
  if (blk < 1024) {
    const int z = blk >> 8;
    const float* W = (z == 0) ? W0 : (z == 1) ? W1 : (z == 2) ? W2 : W3;
    unsigned short* WT = (z == 0) ? T0 : (z == 1) ? T1 : (z == 2) ? T2 : T3;
    const int n0 = (blk & 15) * 64, k0 = ((blk >> 4) & 15) * 64;
    const int r = t >> 4, c4 = (t & 15) * 4;
#pragma unroll
    for (int i = 0; i < 4; ++i) {
      const int k = i * 16 + r;
      const float4 v = *(const float4*)&W[(k0 + k) * 1024 + n0 + c4];
      tile[k][c4 + 0] = f2bf(v.x);
      tile[k][c4 + 1] = f2bf(v.y);
      tile[k][c4 + 2] = f2bf(v.z);
      tile[k][c4 + 3] = f2bf(v.w);
    }
    __syncthreads();
#pragma unroll
    for (int i = 0; i < 4; ++i) {
      const int n = i * 16 + r;
      ushort4 o;
      o.x = tile[c4 + 0][n];
      o.y = tile[c4 + 1][n];
      o.z = tile[c4 + 2][n];
      o.w = tile[c4 + 3][n];
      *(ushort4*)&WT[(n0 + n) * 1024 + k0 + c4] = o;
    }
  } else {
    const int c = blk - 1024;  // 0..6143
    const int z = c >> 11, sub = c & 2047;
    const float* src = (z == 0) ? qs : (z == 1) ? ks : vs;
    unsigned short* dst = (z == 0) ? Qc : (z == 1) ? Kc : Vc;
    const size_t base = ((size_t)sub * 256 + t) * 8;
    const float4 f0 = *(const float4*)(src + base);
    const float4 f1 = *(const float4*)(src + base + 4);
    const uint4 o{pk2bf(f0.x, f0.y), pk2bf(f0.z, f0.w), pk2bf(f1.x, f1.y), pk2bf(f1.z, f1.w)};
    *(uint4*)(dst + base) = o;
  }
}

// legacy wt-only (fallback path when ws too small for cvt buffers)
__global__ __launch_bounds__(256) void wt4_kernel(const float* __restrict__ W0,
                                                  const float* __restrict__ W1,
                                                  const float* __restrict__ W2,
                                                  const float* __restrict__ W3,
                                                  unsigned short* __restrict__ T0,
                                                  unsigned short* __restrict__ T1,
                                                  unsigned short* __restrict__ T2,
                                                  unsigned short* __restrict__ T3) {
  __shared__ unsigned short tile[64][68];
  const int z = blockIdx.z;
  const float* W = (z == 0) ? W0 : (z == 1) ? W1 : (z == 2) ? W2 : W3;
  unsigned short* WT = (z == 0) ? T0 : (z == 1) ? T1 : (z == 2) ? T2 : T3;
  const int t = threadIdx.x;
  const int n0 = blockIdx.x * 64, k0 = blockIdx.y * 64;
  const int r = t >> 4, c4 = (t & 15) * 4;
#pragma unroll
  for (int i = 0; i < 4; ++i) {
    const int k = i * 16 + r;
    const float4 v = *(const float4*)&W[(k0 + k) * 1024 + n0 + c4];
    tile[k][c4 + 0] = f2bf(v.x);
    tile[k][c4 + 1] = f2bf(v.y);
    tile[k][c4 + 2] = f2bf(v.z);
    tile[k][c4 + 3] = f2bf(v.w);
  }
  __syncthreads();
#pragma unroll
  for (int i = 0; i < 4; ++i) {
    const int n = i * 16 + r;
    ushort4 o;
    o.x = tile[c4 + 0][n];
    o.y = tile[c4 + 1][n];
    o.z = tile[c4 + 2][n];
    o.w = tile[c4 + 3][n];
    *(ushort4*)&WT[(n0 + n) * 1024 + k0 + c4] = o;
  }
}

// ---------------- fused QKV GEMM, all-bf16, 3-buf counted-vmcnt pipeline ----------------
__global__ __launch_bounds__(256, 3) void qkv_gemm_bf16(const unsigned short* __restrict__ Aq,
                                                        const unsigned short* __restrict__ Ak,
                                                        const unsigned short* __restrict__ Av,
                                                        const unsigned short* __restrict__ Wq,
                                                        const unsigned short* __restrict__ Wk,
                                                        const unsigned short* __restrict__ Wv,
                                                        const float* __restrict__ bq,
                                                        const float* __restrict__ bk,
                                                        const float* __restrict__ bv,
                                                        unsigned short* __restrict__ Qb,
                                                        unsigned short* __restrict__ Kb,
                                                        unsigned short* __restrict__ Vt,
                                                        const float qscale) {
  __shared__ char AsB[3][8192];
  __shared__ char BsB[3][8192];
  const int t = threadIdx.x;
  const int z = blockIdx.z;
  const unsigned short* A = (z == 0) ? Aq : (z == 1) ? Ak : Av;
  const unsigned short* BT = (z == 0) ? Wq : (z == 1) ? Wk : Wv;
  const float* bias = (z == 0) ? bq : (z == 1) ? bk : bv;
  const float scale = (z == 0) ? qscale : 1.0f;

  const int lane = t & 63, w = t >> 6;
  const int g = lane >> 4, li = lane & 15;
  const int wr = (w >> 1) * 64, wc = (w & 1) * 64;
  const int lin = blockIdx.x + 8 * blockIdx.y;
  const int work = (lin & 7) * 32 + (lin >> 3);
  const int m0 = (work >> 3) * 128, n0 = (work & 7) * 128;

  const int r1 = t >> 2, c1 = (t & 3) ^ ((r1 >> 1) & 3);
  const int r2 = r1 + 64, c2 = (t & 3) ^ ((r2 >> 1) & 3);

  auto stage = [&](int kt, int buf) {
    const int k0 = kt * 32;
    gl_lds16(A + (size_t)(m0 + r1) * 1024 + k0 + c1 * 8, &AsB[buf][0] + (w << 10));
    gl_lds16(A + (size_t)(m0 + r2) * 1024 + k0 + c2 * 8, &AsB[buf][0] + 4096 + (w << 10));
    gl_lds16(BT + (size_t)(n0 + r1) * 1024 + k0 + c1 * 8, &BsB[buf][0] + (w << 10));
    gl_lds16(BT + (size_t)(n0 + r2) * 1024 + k0 + c2 * 8, &BsB[buf][0] + 4096 + (w << 10));
  };

  f32x4 acc[4][4] = {};
  stage(0, 0);
  stage(1, 1);
  asm volatile("s_waitcnt vmcnt(4)" ::: "memory");
  asm volatile("s_barrier" ::: "memory");

  int cur = 0;
  for (int kt = 0; kt < 32; ++kt) {
    if (kt < 30) {
      int nb = cur + 2; if (nb >= 3) nb -= 3;
      stage(kt + 2, nb);
    }
    const char* Ab = &AsB[cur][0];
    const char* Bb = &BsB[cur][0];
    FragU a[4], bf[4];
#pragma unroll
    for (int i = 0; i < 4; ++i) {
      const int ra = wr + i * 16 + li;
      a[i].u = *(const uint4*)(Ab + ra * 64 + ((g ^ ((ra >> 1) & 3)) << 4));
      const int rb = wc + i * 16 + li;
      bf[i].u = *(const uint4*)(Bb + rb * 64 + ((g ^ ((rb >> 1) & 3)) << 4));
    }
#pragma unroll
    for (int fm = 0; fm < 4; ++fm)
#pragma unroll
      for (int fn = 0; fn < 4; ++fn)
        acc[fm][fn] = __builtin_amdgcn_mfma_f32_16x16x32_bf16(a[fm].v, bf[fn].v, acc[fm][fn], 0, 0, 0);

    if (kt < 30) {
      asm volatile("s_waitcnt vmcnt(4)" ::: "memory");
    } else if (kt == 30) {
      asm volatile("s_waitcnt vmcnt(0)" ::: "memory");
    }
    if (kt < 31) asm volatile("s_barrier" ::: "memory");
    cur = (cur == 2) ? 0 : cur + 1;
  }

  unsigned short* OutN = (z == 0) ? Qb : Kb;
#pragma unroll
  for (int fn = 0; fn < 4; ++fn) {
    const int n = n0 + wc + fn * 16 + li;
    const float bv2 = bias[n];
#pragma unroll
    for (int fm = 0; fm < 4; ++fm) {
      const int mb = m0 + wr + fm * 16 + g * 4;
      const f32x4 v = acc[fm][fn];
      ushort4 pk;
      pk.x = f2bf((v[0] + bv2) * scale);
      pk.y = f2bf((v[1] + bv2) * scale);
      pk.z = f2bf((v[2] + bv2) * scale);
      pk.w = f2bf((v[3] + bv2) * scale);
      if (z == 2) {
        const int bb = mb >> 11, s = mb & 2047;
        *(ushort4*)&Vt[(size_t)(bb * 1024 + n) * 2048 + s] = pk;
      } else {
        unsigned short* o = OutN;
        o[(size_t)(mb + 0) * 1024 + n] = pk.x;
        o[(size_t)(mb + 1) * 1024 + n] = pk.y;
        o[(size_t)(mb + 2) * 1024 + n] = pk.z;
        o[(size_t)(mb + 3) * 1024 + n] = pk.w;
      }
    }
  }
}

// ---------------- fallback fused QKV GEMM (fp32 A reg-convert, 2-buf) -------------------
__global__ __launch_bounds__(256, 3) void qkv_gemm_f32(const float* __restrict__ Aq,
                                                       const float* __restrict__ Ak,
                                                       const float* __restrict__ Av,
                                                       const unsigned short* __restrict__ Wq,
                                                       const unsigned short* __restrict__ Wk,
                                                       const unsigned short* __restrict__ Wv,
                                                       const float* __restrict__ bq,
                                                       const float* __restrict__ bk,
                                                       const float* __restrict__ bv,
                                                       unsigned short* __restrict__ Qb,
                                                       unsigned short* __restrict__ Kb,
                                                       unsigned short* __restrict__ Vt,
                                                       const float qscale) {
  __shared__ unsigned short As[2][128 * 32];
  __shared__ unsigned short Bs[2][128 * 32];
  const int t = threadIdx.x;
  const int z = blockIdx.z;
  const float* A = (z == 0) ? Aq : (z == 1) ? Ak : Av;
  const unsigned short* BT = (z == 0) ? Wq : (z == 1) ? Wk : Wv;
  const float* bias = (z == 0) ? bq : (z == 1) ? bk : bv;
  const float scale = (z == 0) ? qscale : 1.0f;

  const int lane = t & 63, w = t >> 6;
  const int g = lane >> 4, li = lane & 15;
  const int wr = (w >> 1) * 64, wc = (w & 1) * 64;
  const int lin = blockIdx.x + 8 * blockIdx.y;
  const int work = (lin & 7) * 32 + (lin >> 3);
  const int m0 = (work >> 3) * 128, n0 = (work & 7) * 128;

  const int arow = t >> 1, ac0 = (t & 1) * 2, asw = (arow >> 1) & 3;
  const int br1 = t >> 2, bg1 = (t & 3) ^ ((br1 >> 1) & 3);
  const int br2 = br1 + 64, bg2 = (t & 3) ^ ((br2 >> 1) & 3);

  auto stageB = [&](int k0, int buf) {
    gl_lds16(BT + (size_t)(n0 + br1) * 1024 + k0 + bg1 * 8, (char*)&Bs[buf][0] + (w << 10));
    gl_lds16(BT + (size_t)(n0 + br2) * 1024 + k0 + bg2 * 8, (char*)&Bs[buf][0] + 4096 + (w << 10));
  };

  uint4 ar0, ar1;
  auto loadA = [&](int k0) {
    const float* ga = A + (size_t)(m0 + arow) * 1024 + k0 + ac0 * 8;
    const float4 f0 = *(const float4*)(ga + 0), f1 = *(const float4*)(ga + 4);
    const float4 f2 = *(const float4*)(ga + 8), f3 = *(const float4*)(ga + 12);
    ar0 = uint4{pk2bf(f0.x, f0.y), pk2bf(f0.z, f0.w), pk2bf(f1.x, f1.y), pk2bf(f1.z, f1.w)};
    ar1 = uint4{pk2bf(f2.x, f2.y), pk2bf(f2.z, f2.w), pk2bf(f3.x, f3.y), pk2bf(f3.z, f3.w)};
  };
  auto storeA = [&](int buf) {
    char* ab = (char*)&As[buf][0] + arow * 64;
    *(uint4*)(ab + ((ac0 ^ asw) << 4)) = ar0;
    *(uint4*)(ab + (((ac0 + 1) ^ asw) << 4)) = ar1;
  };

  f32x4 acc[4][4] = {};
  stageB(0, 0);
  loadA(0);
  storeA(0);
  __syncthreads();
  int cur = 0;
  for (int k0 = 0; k0 < 1024; k0 += 32) {
    const bool more = (k0 + 32) < 1024;
    if (more) {
      stageB(k0 + 32, cur ^ 1);
      loadA(k0 + 32);
    }
    const char* Ab = (const char*)&As[cur][0];
    const char* Bb = (const char*)&Bs[cur][0];
    FragU a[4], bf[4];
#pragma unroll
    for (int i = 0; i < 4; ++i) {
      const int rowa = wr + i * 16 + li;
      a[i].u = *(const uint4*)(Ab + rowa * 64 + (((g) ^ ((rowa >> 1) & 3)) << 4));
      const int rowb = wc + i * 16 + li;
      bf[i].u = *(const uint4*)(Bb + rowb * 64 + (((g) ^ ((rowb >> 1) & 3)) << 4));
    }
#pragma unroll
    for (int fm = 0; fm < 4; ++fm)
#pragma unroll
      for (int fn = 0; fn < 4; ++fn)
        acc[fm][fn] = __builtin_amdgcn_mfma_f32_16x16x32_bf16(a[fm].v, bf[fn].v, acc[fm][fn], 0, 0, 0);
    if (more) storeA(cur ^ 1);
    __syncthreads();
    cur ^= 1;
  }

  unsigned short* OutN = (z == 0) ? Qb : Kb;
#pragma unroll
  for (int fn = 0; fn < 4; ++fn) {
    const int n = n0 + wc + fn * 16 + li;
    const float bv2 = bias[n];
#pragma unroll
    for (int fm = 0; fm < 4; ++fm) {
      const int mb = m0 + wr + fm * 16 + g * 4;
      const f32x4 v = acc[fm][fn];
      ushort4 pk;
      pk.x = f2bf((v[0] + bv2) * scale);
      pk.y = f2bf((v[1] + bv2) * scale);
      pk.z = f2bf((v[2] + bv2) * scale);
      pk.w = f2bf((v[3] + bv2) * scale);
      if (z == 2) {
        const int bb = mb >> 11, s = mb & 2047;
        *(ushort4*)&Vt[(size_t)(bb * 1024 + n) * 2048 + s] = pk;
      } else {
        unsigned short* o = OutN;
        o[(size_t)(mb + 0) * 1024 + n] = pk.x;
        o[(size_t)(mb + 1) * 1024 + n] = pk.y;
        o[(size_t)(mb + 2) * 1024 + n] = pk.z;
        o[(size_t)(mb + 3) * 1024 + n] = pk.w;
      }
    }
  }
}

// ---------------- out GEMM: fp32 out = ctx(bf16) @ WoT^T + bo (3-buf counted vmcnt) -----
__global__ __launch_bounds__(256, 3) void out_gemm(const unsigned short* __restrict__ A,
                                                   const unsigned short* __restrict__ BT,
                                                   const float* __restrict__ bias,
                                                   float* __restrict__ Out) {
  __shared__ char AsB[3][8192];
  __shared__ char BsB[3][8192];
  const int t = threadIdx.x;
  const int lane = t & 63, w = t >> 6;
  const int g = lane >> 4, li = lane & 15;
  const int wr = (w >> 1) * 64, wc = (w & 1) * 64;
  const int lin = blockIdx.x + 8 * blockIdx.y;
  const int work = (lin & 7) * 32 + (lin >> 3);
  const int m0 = (work >> 3) * 128, n0 = (work & 7) * 128;

  const int r1 = t >> 2, c1 = (t & 3) ^ ((r1 >> 1) & 3);
  const int r2 = r1 + 64, c2 = (t & 3) ^ ((r2 >> 1) & 3);

  auto stage = [&](int kt, int buf) {
    const int k0 = kt * 32;
    gl_lds16(A + (size_t)(m0 + r1) * 1024 + k0 + c1 * 8, &AsB[buf][0] + (w << 10));
    gl_lds16(A + (size_t)(m0 + r2) * 1024 + k0 + c2 * 8, &AsB[buf][0] + 4096 + (w << 10));
    gl_lds16(BT + (size_t)(n0 + r1) * 1024 + k0 + c1 * 8, &BsB[buf][0] + (w << 10));
    gl_lds16(BT + (size_t)(n0 + r2) * 1024 + k0 + c2 * 8, &BsB[buf][0] + 4096 + (w << 10));
  };

  f32x4 acc[4][4] = {};
  stage(0, 0);
  stage(1, 1);
  asm volatile("s_waitcnt vmcnt(4)" ::: "memory");
  asm volatile("s_barrier" ::: "memory");

  int cur = 0;
  for (int kt = 0; kt < 32; ++kt) {
    if (kt < 30) {
      int nb = cur + 2; if (nb >= 3) nb -= 3;
      stage(kt + 2, nb);
    }
    const char* Ab = &AsB[cur][0];
    const char* Bb = &BsB[cur][0];
    FragU a[4], bf[4];
#pragma unroll
    for (int i = 0; i < 4; ++i) {
      const int ra = wr + i * 16 + li;
      a[i].u = *(const uint4*)(Ab + ra * 64 + ((g ^ ((ra >> 1) & 3)) << 4));
      const int rb = wc + i * 16 + li;
      bf[i].u = *(const uint4*)(Bb + rb * 64 + ((g ^ ((rb >> 1) & 3)) << 4));
    }
#pragma unroll
    for (int fm = 0; fm < 4; ++fm)
#pragma unroll
      for (int fn = 0; fn < 4; ++fn)
        acc[fm][fn] = __builtin_amdgcn_mfma_f32_16x16x32_bf16(a[fm].v, bf[fn].v, acc[fm][fn], 0, 0, 0);

    if (kt < 30) {
      asm volatile("s_waitcnt vmcnt(4)" ::: "memory");
    } else if (kt == 30) {
      asm volatile("s_waitcnt vmcnt(0)" ::: "memory");
    }
    if (kt < 31) asm volatile("s_barrier" ::: "memory");
    cur = (cur == 2) ? 0 : cur + 1;
  }

#pragma unroll
  for (int fn = 0; fn < 4; ++fn) {
    const int n = n0 + wc + fn * 16 + li;
    const float bv = bias[n];
#pragma unroll
    for (int fm = 0; fm < 4; ++fm) {
      const int mb = m0 + wr + fm * 16 + g * 4;
      const f32x4 v = acc[fm][fn];
#pragma unroll
      for (int r = 0; r < 4; ++r) Out[(size_t)(mb + r) * 1024 + n] = v[r] + bv;
    }
  }
}

// ---------------- flash attention, kv-parity split, gl_lds staging ----------------
// 1024 blocks (XCD-swizzled), 4 waves: wave w = q-sub (w>>1)*32, kv-parity w&1.
// K/V staged via global_load_lds with pre-swizzled per-lane SOURCE (linear LDS dest):
// LDS chunk cc = w*128 + j*64 + lane -> row r = cc>>3, slot ss = cc&7 holds source chunk
// s = ss ^ (r&7); since r&7 = (lane>>3)&7, s = (lane&7)^((lane>>3)&7) (j-invariant).
// Single 32KB buffer, per-iter {barrier; stage; vmcnt(0); barrier} drain — hidden by
// 4 blocks/CU TLP. No reg staging -> no spill (R10 lesson: (256,4) caps VGPR at 64).
__global__ __launch_bounds__(256, 2) void attn_kernel(const unsigned short* __restrict__ Qb,
                                                      const unsigned short* __restrict__ Kb,
                                                      const unsigned short* __restrict__ Vt,
                                                      const int* __restrict__ mask,
                                                      unsigned short* __restrict__ ctx) {
  __shared__ char smem[32768];  // K even:0..8K, K odd:8..16K, V even:16..24K, V odd:24..32K
  const int t = threadIdx.x, lane = t & 63, w = t >> 6;
  const int l31 = lane & 31, hi = lane >> 5;
  const int p = w & 1;
  const int d0 = blockIdx.x;
  const int work = (d0 & 7) * 128 + (d0 >> 3);
  const int qblk = work & 31, bh = work >> 5;
  const int b = bh >> 4, h = bh & 15;
  const int qrow = b * 2048 + qblk * 64 + (w >> 1) * 32 + l31;

  char* Ksp = smem + p * 8192;
  char* Vsp = smem + 16384 + p * 8192;

  const unsigned short* Kbase = Kb + (size_t)(b * 2048) * 1024 + h * 64;
  const unsigned short* Vbase = Vt + (size_t)(b * 1024 + h * 64) * 2048;

  // staging geometry: wave w stages rows [w*16 + j*8 + (lane>>3)] of each 64-row tile
  const int srw = (lane >> 3);             // 0..7
  const int ssc = (lane & 7) ^ srw;        // pre-swizzled source chunk (j-invariant)

  int mv_next;
  auto stage = [&](int i) {
    const int ke = 2 * i * 64, ko = ke + 64;
#pragma unroll
    for (int j = 0; j < 2; ++j) {
      const int rr = w * 16 + j * 8 + srw;
      char* ldsb = smem + w * 2048 + j * 1024;
      gl_lds16(Kbase + (size_t)(ke + rr) * 1024 + ssc * 8, ldsb);
      gl_lds16(Kbase + (size_t)(ko + rr) * 1024 + ssc * 8, ldsb + 8192);
      gl_lds16(Vbase + (size_t)rr * 2048 + ke + ssc * 8, ldsb + 16384);
      gl_lds16(Vbase + (size_t)rr * 2048 + ko + ssc * 8, ldsb + 24576);
    }
    mv_next = mask[b * 2048 + (2 * i + p) * 64 + lane];
  };

  FragU qf[4];
  {
    const unsigned short* qb = Qb + (size_t)qrow * 1024 + h * 64 + hi * 8;
#pragma unroll
    for (int dc = 0; dc < 4; ++dc) qf[dc].u = *(const uint4*)(qb + dc * 16);
  }

  stage(0);
  asm volatile("s_waitcnt vmcnt(0)" ::: "memory");
  int mv_cur = mv_next;
  asm volatile("s_barrier" ::: "memory");
  __builtin_amdgcn_sched_barrier(0);

  f32x16 acc[2] = {};
  float m_run = 8.0f, l_run = 0.f;

  for (int i = 0; i < 16; ++i) {
    const int mvcur = mv_cur;

    // QK^T from Ks[p]
    f32x16 sc[2] = {};
    {
      __builtin_amdgcn_s_setprio(1);
#pragma unroll
      for (int t2 = 0; t2 < 2; ++t2) {
        const int row = t2 * 32 + l31;
        const int sw = (row & 7) << 4;
        const int rb = row * 128;
#pragma unroll
        for (int dc = 0; dc < 4; ++dc) {
          FragU kf;
          kf.u = *(const uint4*)(Ksp + rb + ((16 * (dc * 2 + hi)) ^ sw));
          sc[t2] = __builtin_amdgcn_mfma_f32_32x32x16_bf16(kf.v, qf[dc].v, sc[t2], 0, 0, 0);
        }
      }
      __builtin_amdgcn_s_setprio(0);
    }

    if (!__all(mvcur != 0)) {
#pragma unroll
      for (int t2 = 0; t2 < 2; ++t2)
#pragma unroll
        for (int r = 0; r < 16; ++r) {
          const int kvv = t2 * 32 + (r & 3) + 8 * (r >> 2) + 4 * hi;
          sc[t2][r] += (__shfl(mvcur, kvv, 64) ? 0.f : -30000.f);
        }
    }

    float pm = sc[0][0];
#pragma unroll
    for (int t2 = 0; t2 < 2; ++t2)
#pragma unroll
      for (int r = 0; r < 16; ++r) pm = fmaxf(pm, sc[t2][r]);
    pm = fmaxf(pm, __shfl_xor(pm, 32, 64));

    if (!__all(pm <= m_run + 8.f)) {
      const float m_new = fmaxf(m_run, pm);
      const float rsc = __builtin_amdgcn_exp2f(m_run - m_new);
      m_run = m_new;
      l_run *= rsc;
#pragma unroll
      for (int dt = 0; dt < 2; ++dt)
#pragma unroll
        for (int r = 0; r < 16; ++r) acc[dt][r] *= rsc;
    }

    float rs = 0.f;
#pragma unroll
    for (int t2 = 0; t2 < 2; ++t2)
#pragma unroll
      for (int r = 0; r < 16; ++r) {
        const float e = __builtin_amdgcn_exp2f(sc[t2][r] - m_run);
        sc[t2][r] = e;
        rs += e;
      }
    l_run += rs;

    FragU pf[4];
#pragma unroll
    for (int ks = 0; ks < 4; ++ks) {
      const int t2 = ks >> 1, s8 = (ks & 1) * 8;
      uint32_t U = pk2bf(sc[t2][s8 + 0], sc[t2][s8 + 1]);
      uint32_t V2 = pk2bf(sc[t2][s8 + 2], sc[t2][s8 + 3]);
      uint32_t X = pk2bf(sc[t2][s8 + 4], sc[t2][s8 + 5]);
      uint32_t Y = pk2bf(sc[t2][s8 + 6], sc[t2][s8 + 7]);
      asm("v_permlane32_swap_b32 %0, %1" : "+v"(U), "+v"(X));
      asm("v_permlane32_swap_b32 %0, %1" : "+v"(V2), "+v"(Y));
      pf[ks].u = uint4{U, V2, X, Y};
    }

    // PV from Vs[p]
    {
      __builtin_amdgcn_s_setprio(1);
#pragma unroll
      for (int dt = 0; dt < 2; ++dt) {
        const int drow = dt * 32 + l31;
        const int sw = (drow & 7) << 4;
        const int rb = drow * 128;
#pragma unroll
        for (int ks = 0; ks < 4; ++ks) {
          FragU vf;
          vf.u = *(const uint4*)(Vsp + rb + ((16 * (ks * 2 + hi)) ^ sw));
          acc[dt] = __builtin_amdgcn_mfma_f32_32x32x16_bf16(vf.v, pf[ks].v, acc[dt], 0, 0, 0);
        }
      }
      __builtin_amdgcn_s_setprio(0);
    }

    if (i < 15) {
      asm volatile("s_barrier" ::: "memory");  // all waves done reading iter-i LDS
      stage(i + 1);                            // DMA into the (now free) buffer
      asm volatile("s_waitcnt vmcnt(0)" ::: "memory");
      mv_cur = mv_next;
      asm volatile("s_barrier" ::: "memory");
      __builtin_amdgcn_sched_barrier(0);
    }
  }

  // ---- pair combine: waves (2k, 2k+1) share q rows; merge online-softmax states ----
  asm volatile("s_barrier" ::: "memory");
  float* exch = (float*)smem;
  float* myex = exch + (w >> 1) * (64 * 37) + lane * 37;
  if (p) {
    const float l_red = l_run + __shfl_xor(l_run, 32, 64);
#pragma unroll
    for (int dt = 0; dt < 2; ++dt)
#pragma unroll
      for (int r = 0; r < 16; ++r) myex[dt * 16 + r] = acc[dt][r];
    myex[32] = m_run;
    myex[33] = l_red;
  }
  asm volatile("s_waitcnt lgkmcnt(0)" ::: "memory");
  asm volatile("s_barrier" ::: "memory");
  if (!p) {
    const float m_b = myex[32], l_b = myex[33];
    const float l_a = l_run + __shfl_xor(l_run, 32, 64);
    const float m = fmaxf(m_run, m_b);
    const float ea = __builtin_amdgcn_exp2f(m_run - m);
    const float eb = __builtin_amdgcn_exp2f(m_b - m);
    const float inv_l = 1.0f / (l_a * ea + l_b * eb);
    unsigned short* cb = ctx + (size_t)qrow * 1024 + h * 64;
#pragma unroll
    for (int dt = 0; dt < 2; ++dt)
#pragma unroll
      for (int rq = 0; rq < 4; ++rq) {
        float v0 = (acc[dt][rq * 4 + 0] * ea + myex[dt * 16 + rq * 4 + 0] * eb) * inv_l;
        float v1 = (acc[dt][rq * 4 + 1] * ea + myex[dt * 16 + rq * 4 + 1] * eb) * inv_l;
        float v2 = (acc[dt][rq * 4 + 2] * ea + myex[dt * 16 + rq * 4 + 2] * eb) * inv_l;
        float v3 = (acc[dt][rq * 4 + 3] * ea + myex[dt * 16 + rq * 4 + 3] * eb) * inv_l;
        uint2 o;
        o.x = pk2bf(v0, v1);
        o.y = pk2bf(v2, v3);
        *(uint2*)(cb + dt * 32 + rq * 8 + hi * 4) = o;
      }
  }
}

extern "C" void kernel_launch(void* const* d_in, const int* in_sizes, int n_in,
                              void* d_out, int out_size, void* d_ws, size_t ws_size,
                              hipStream_t stream) {
  const float* query = (const float*)d_in[0];
  const float* key = (const float*)d_in[1];
  const float* value = (const float*)d_in[2];
  const int* mask = (const int*)d_in[3];
  const float* Wq = (const float*)d_in[4];
  const float* bq = (const float*)d_in[5];
  const float* Wk = (const float*)d_in[6];
  const float* bk = (const float*)d_in[7];
  const float* Wv = (const float*)d_in[8];
  const float* bv = (const float*)d_in[9];
  const float* Wo = (const float*)d_in[10];
  const float* bo = (const float*)d_in[11];
  float* out = (float*)d_out;

  const size_t MB = 1024 * 1024;
  if (ws_size < 40 * MB) return;
  char* ws = (char*)d_ws;
  unsigned short* WqT = (unsigned short*)(ws);
  unsigned short* WkT = (unsigned short*)(ws + 2 * MB);
  unsigned short* WvT = (unsigned short*)(ws + 4 * MB);
  unsigned short* WoT = (unsigned short*)(ws + 6 * MB);
  unsigned short* Qb = (unsigned short*)(ws + 8 * MB);
  unsigned short* Kb = (unsigned short*)(ws + 16 * MB);
  unsigned short* Vt = (unsigned short*)(ws + 24 * MB);
  unsigned short* ctx = (unsigned short*)(ws + 32 * MB);

  const dim3 tb(256);
  const float qscale = 0.125f * 1.4426950408889634f;

  if (ws_size >= 64 * MB) {
    unsigned short* Qc = (unsigned short*)(ws + 40 * MB);
    unsigned short* Kc = (unsigned short*)(ws + 48 * MB);
    unsigned short* Vc = (unsigned short*)(ws + 56 * MB);
    prep_kernel<<<dim3(7168), tb, 0, stream>>>(Wq, Wk, Wv, Wo, WqT, WkT, WvT, WoT,
                                               query, key, value, Qc, Kc, Vc);
    qkv_gemm_bf16<<<dim3(8, 32, 3), tb, 0, stream>>>(Qc, Kc, Vc, WqT, WkT, WvT,
                                                     bq, bk, bv, Qb, Kb, Vt, qscale);
  } else {
    wt4_kernel<<<dim3(16, 16, 4), tb, 0, stream>>>(Wq, Wk, Wv, Wo, WqT, WkT, WvT, WoT);
    qkv_gemm_f32<<<dim3(8, 32, 3), tb, 0, stream>>>(query, key, value, WqT, WkT, WvT,
                                                    bq, bk, bv, Qb, Kb, Vt, qscale);
  }

  attn_kernel<<<dim3(1024), tb, 0, stream>>>(Qb, Kb, Vt, mask, ctx);

  out_gemm<<<dim3(8, 32), tb, 0, stream>>>(ctx, WoT, bo, out);
}

// Round 12
// 125.071 us; speedup vs baseline: 1.8003x; 1.0423x over previous
//
#include <hip/hip_runtime.h>
#include <hip/hip_bf16.h>
#include <stdint.h>

typedef short s16x8 __attribute__((ext_vector_type(8)));
typedef float f32x4 __attribute__((ext_vector_type(4)));
typedef float f32x16 __attribute__((ext_vector_type(16)));

union FragU { uint4 u; s16x8 v; };

static __device__ __forceinline__ uint32_t pk2bf(float a, float b) {
  union { __hip_bfloat162 h; uint32_t u; } cv;
  cv.h = __float22bfloat162_rn(make_float2(a, b));
  return cv.u;
}

static __device__ __forceinline__ unsigned short f2bf(float f) {
  union { float f; uint32_t u; } x; x.f = f;
  uint32_t r = x.u + 0x7FFFu + ((x.u >> 16) & 1u);  // RNE
  return (unsigned short)(r >> 16);
}

static __device__ __forceinline__ void gl_lds16(const void* g, void* lds_wave_base) {
  __builtin_amdgcn_global_load_lds(
      (const __attribute__((address_space(1))) uint32_t*)(uintptr_t)g,
      (__attribute__((address_space(3))) uint32_t*)(uintptr_t)lds_wave_base, 16, 0, 0);
}

// ---------------- prep: 4x weight transpose (blocks 0-1023) + qkv fp32->bf16 cvt ----------
__global__ __launch_bounds__(256) void prep_kernel(const float* __restrict__ W0,
                                                   const float* __restrict__ W1,
                                                   const float* __restrict__ W2,
                                                   const float* __restrict__ W3,
                                                   unsigned short* __restrict__ T0,
                                                   unsigned short* __restrict__ T1,
                                                   unsigned short* __restrict__ T2,
                                                   unsigned short* __restrict__ T3,
                                                   const float* __restrict__ qs,
                                                   const float* __restrict__ ks,
                                                   const float* __restrict__ vs,
                                                   unsigned short* __restrict__ Qc,
                                                   unsigned short* __restrict__ Kc,
                                                   unsigned short* __restrict__ Vc) {
  __shared__ unsigned short tile[64][68];
  const int blk = blockIdx.x;
  const int t = threadIdx.x;
  if (blk < 1024) {
    const int z = blk >> 8;
    const float* W = (z == 0) ? W0 : (z == 1) ? W1 : (z == 2) ? W2 : W3;
    unsigned short* WT = (z == 0) ? T0 : (z == 1) ? T1 : (z == 2) ? T2 : T3;
    const int n0 = (blk & 15) * 64, k0 = ((blk >> 4) & 15) * 64;
    const int r = t >> 4, c4 = (t & 15) * 4;
#pragma unroll
    for (int i = 0; i < 4; ++i) {
      const int k = i * 16 + r;
      const float4 v = *(const float4*)&W[(k0 + k) * 1024 + n0 + c4];
      tile[k][c4 + 0] = f2bf(v.x);
      tile[k][c4 + 1] = f2bf(v.y);
      tile[k][c4 + 2] = f2bf(v.z);
      tile[k][c4 + 3] = f2bf(v.w);
    }
    __syncthreads();
#pragma unroll
    for (int i = 0; i < 4; ++i) {
      const int n = i * 16 + r;
      ushort4 o;
      o.x = tile[c4 + 0][n];
      o.y = tile[c4 + 1][n];
      o.z = tile[c4 + 2][n];
      o.w = tile[c4 + 3][n];
      *(ushort4*)&WT[(n0 + n) * 1024 + k0 + c4] = o;
    }
  } else {
    const int c = blk - 1024;  // 0..6143
    const int z = c >> 11, sub = c & 2047;
    const float* src = (z == 0) ? qs : (z == 1) ? ks : vs;
    unsigned short* dst = (z == 0) ? Qc : (z == 1) ? Kc : Vc;
    const size_t base = ((size_t)sub * 256 + t) * 8;
    const float4 f0 = *(const float4*)(src + base);
    const float4 f1 = *(const float4*)(src + base + 4);
    const uint4 o{pk2bf(f0.x, f0.y), pk2bf(f0.z, f0.w), pk2bf(f1.x, f1.y), pk2bf(f1.z, f1.w)};
    *(uint4*)(dst + base) = o;
  }
}

// legacy wt-only (fallback path when ws too small for cvt buffers)
__global__ __launch_bounds__(256) void wt4_kernel(const float* __restrict__ W0,
                                                  const float* __restrict__ W1,
                                                  const float* __restrict__ W2,
                                                  const float* __restrict__ W3,
                                                  unsigned short* __restrict__ T0,
                                                  unsigned short* __restrict__ T1,
                                                  unsigned short* __restrict__ T2,
                                                  unsigned short* __restrict__ T3) {
  __shared__ unsigned short tile[64][68];
  const int z = blockIdx.z;
  const float* W = (z == 0) ? W0 : (z == 1) ? W1 : (z == 2) ? W2 : W3;
  unsigned short* WT = (z == 0) ? T0 : (z == 1) ? T1 : (z == 2) ? T2 : T3;
  const int t = threadIdx.x;
  const int n0 = blockIdx.x * 64, k0 = blockIdx.y * 64;
  const int r = t >> 4, c4 = (t & 15) * 4;
#pragma unroll
  for (int i = 0; i < 4; ++i) {
    const int k = i * 16 + r;
    const float4 v = *(const float4*)&W[(k0 + k) * 1024 + n0 + c4];
    tile[k][c4 + 0] = f2bf(v.x);
    tile[k][c4 + 1] = f2bf(v.y);
    tile[k][c4 + 2] = f2bf(v.z);
    tile[k][c4 + 3] = f2bf(v.w);
  }
  __syncthreads();
#pragma unroll
  for (int i = 0; i < 4; ++i) {
    const int n = i * 16 + r;
    ushort4 o;
    o.x = tile[c4 + 0][n];
    o.y = tile[c4 + 1][n];
    o.z = tile[c4 + 2][n];
    o.w = tile[c4 + 3][n];
    *(ushort4*)&WT[(n0 + n) * 1024 + k0 + c4] = o;
  }
}

// ---------------- fused QKV GEMM, all-bf16, 3-buf counted-vmcnt pipeline ----------------
__global__ __launch_bounds__(256, 3) void qkv_gemm_bf16(const unsigned short* __restrict__ Aq,
                                                        const unsigned short* __restrict__ Ak,
                                                        const unsigned short* __restrict__ Av,
                                                        const unsigned short* __restrict__ Wq,
                                                        const unsigned short* __restrict__ Wk,
                                                        const unsigned short* __restrict__ Wv,
                                                        const float* __restrict__ bq,
                                                        const float* __restrict__ bk,
                                                        const float* __restrict__ bv,
                                                        unsigned short* __restrict__ Qb,
                                                        unsigned short* __restrict__ Kb,
                                                        unsigned short* __restrict__ Vt,
                                                        const float qscale) {
  __shared__ char AsB[3][8192];
  __shared__ char BsB[3][8192];
  const int t = threadIdx.x;
  const int z = blockIdx.z;
  const unsigned short* A = (z == 0) ? Aq : (z == 1) ? Ak : Av;
  const unsigned short* BT = (z == 0) ? Wq : (z == 1) ? Wk : Wv;
  const float* bias = (z == 0) ? bq : (z == 1) ? bk : bv;
  const float scale = (z == 0) ? qscale : 1.0f;

  const int lane = t & 63, w = t >> 6;
  const int g = lane >> 4, li = lane & 15;
  const int wr = (w >> 1) * 64, wc = (w & 1) * 64;
  const int lin = blockIdx.x + 8 * blockIdx.y;
  const int work = (lin & 7) * 32 + (lin >> 3);
  const int m0 = (work >> 3) * 128, n0 = (work & 7) * 128;

  const int r1 = t >> 2, c1 = (t & 3) ^ ((r1 >> 1) & 3);
  const int r2 = r1 + 64, c2 = (t & 3) ^ ((r2 >> 1) & 3);

  auto stage = [&](int kt, int buf) {
    const int k0 = kt * 32;
    gl_lds16(A + (size_t)(m0 + r1) * 1024 + k0 + c1 * 8, &AsB[buf][0] + (w << 10));
    gl_lds16(A + (size_t)(m0 + r2) * 1024 + k0 + c2 * 8, &AsB[buf][0] + 4096 + (w << 10));
    gl_lds16(BT + (size_t)(n0 + r1) * 1024 + k0 + c1 * 8, &BsB[buf][0] + (w << 10));
    gl_lds16(BT + (size_t)(n0 + r2) * 1024 + k0 + c2 * 8, &BsB[buf][0] + 4096 + (w << 10));
  };

  f32x4 acc[4][4] = {};
  stage(0, 0);
  stage(1, 1);
  asm volatile("s_waitcnt vmcnt(4)" ::: "memory");
  asm volatile("s_barrier" ::: "memory");

  int cur = 0;
  for (int kt = 0; kt < 32; ++kt) {
    if (kt < 30) {
      int nb = cur + 2; if (nb >= 3) nb -= 3;
      stage(kt + 2, nb);
    }
    const char* Ab = &AsB[cur][0];
    const char* Bb = &BsB[cur][0];
    FragU a[4], bf[4];
#pragma unroll
    for (int i = 0; i < 4; ++i) {
      const int ra = wr + i * 16 + li;
      a[i].u = *(const uint4*)(Ab + ra * 64 + ((g ^ ((ra >> 1) & 3)) << 4));
      const int rb = wc + i * 16 + li;
      bf[i].u = *(const uint4*)(Bb + rb * 64 + ((g ^ ((rb >> 1) & 3)) << 4));
    }
#pragma unroll
    for (int fm = 0; fm < 4; ++fm)
#pragma unroll
      for (int fn = 0; fn < 4; ++fn)
        acc[fm][fn] = __builtin_amdgcn_mfma_f32_16x16x32_bf16(a[fm].v, bf[fn].v, acc[fm][fn], 0, 0, 0);

    if (kt < 30) {
      asm volatile("s_waitcnt vmcnt(4)" ::: "memory");
    } else if (kt == 30) {
      asm volatile("s_waitcnt vmcnt(0)" ::: "memory");
    }
    if (kt < 31) asm volatile("s_barrier" ::: "memory");
    cur = (cur == 2) ? 0 : cur + 1;
  }

  unsigned short* OutN = (z == 0) ? Qb : Kb;
#pragma unroll
  for (int fn = 0; fn < 4; ++fn) {
    const int n = n0 + wc + fn * 16 + li;
    const float bv2 = bias[n];
#pragma unroll
    for (int fm = 0; fm < 4; ++fm) {
      const int mb = m0 + wr + fm * 16 + g * 4;
      const f32x4 v = acc[fm][fn];
      ushort4 pk;
      pk.x = f2bf((v[0] + bv2) * scale);
      pk.y = f2bf((v[1] + bv2) * scale);
      pk.z = f2bf((v[2] + bv2) * scale);
      pk.w = f2bf((v[3] + bv2) * scale);
      if (z == 2) {
        const int bb = mb >> 11, s = mb & 2047;
        *(ushort4*)&Vt[(size_t)(bb * 1024 + n) * 2048 + s] = pk;
      } else {
        unsigned short* o = OutN;
        o[(size_t)(mb + 0) * 1024 + n] = pk.x;
        o[(size_t)(mb + 1) * 1024 + n] = pk.y;
        o[(size_t)(mb + 2) * 1024 + n] = pk.z;
        o[(size_t)(mb + 3) * 1024 + n] = pk.w;
      }
    }
  }
}

// ---------------- fallback fused QKV GEMM (fp32 A reg-convert, 2-buf) -------------------
__global__ __launch_bounds__(256, 3) void qkv_gemm_f32(const float* __restrict__ Aq,
                                                       const float* __restrict__ Ak,
                                                       const float* __restrict__ Av,
                                                       const unsigned short* __restrict__ Wq,
                                                       const unsigned short* __restrict__ Wk,
                                                       const unsigned short* __restrict__ Wv,
                                                       const float* __restrict__ bq,
                                                       const float* __restrict__ bk,
                                                       const float* __restrict__ bv,
                                                       unsigned short* __restrict__ Qb,
                                                       unsigned short* __restrict__ Kb,
                                                       unsigned short* __restrict__ Vt,
                                                       const float qscale) {
  __shared__ unsigned short As[2][128 * 32];
  __shared__ unsigned short Bs[2][128 * 32];
  const int t = threadIdx.x;
  const int z = blockIdx.z;
  const float* A = (z == 0) ? Aq : (z == 1) ? Ak : Av;
  const unsigned short* BT = (z == 0) ? Wq : (z == 1) ? Wk : Wv;
  const float* bias = (z == 0) ? bq : (z == 1) ? bk : bv;
  const float scale = (z == 0) ? qscale : 1.0f;

  const int lane = t & 63, w = t >> 6;
  const int g = lane >> 4, li = lane & 15;
  const int wr = (w >> 1) * 64, wc = (w & 1) * 64;
  const int lin = blockIdx.x + 8 * blockIdx.y;
  const int work = (lin & 7) * 32 + (lin >> 3);
  const int m0 = (work >> 3) * 128, n0 = (work & 7) * 128;

  const int arow = t >> 1, ac0 = (t & 1) * 2, asw = (arow >> 1) & 3;
  const int br1 = t >> 2, bg1 = (t & 3) ^ ((br1 >> 1) & 3);
  const int br2 = br1 + 64, bg2 = (t & 3) ^ ((br2 >> 1) & 3);

  auto stageB = [&](int k0, int buf) {
    gl_lds16(BT + (size_t)(n0 + br1) * 1024 + k0 + bg1 * 8, (char*)&Bs[buf][0] + (w << 10));
    gl_lds16(BT + (size_t)(n0 + br2) * 1024 + k0 + bg2 * 8, (char*)&Bs[buf][0] + 4096 + (w << 10));
  };

  uint4 ar0, ar1;
  auto loadA = [&](int k0) {
    const float* ga = A + (size_t)(m0 + arow) * 1024 + k0 + ac0 * 8;
    const float4 f0 = *(const float4*)(ga + 0), f1 = *(const float4*)(ga + 4);
    const float4 f2 = *(const float4*)(ga + 8), f3 = *(const float4*)(ga + 12);
    ar0 = uint4{pk2bf(f0.x, f0.y), pk2bf(f0.z, f0.w), pk2bf(f1.x, f1.y), pk2bf(f1.z, f1.w)};
    ar1 = uint4{pk2bf(f2.x, f2.y), pk2bf(f2.z, f2.w), pk2bf(f3.x, f3.y), pk2bf(f3.z, f3.w)};
  };
  auto storeA = [&](int buf) {
    char* ab = (char*)&As[buf][0] + arow * 64;
    *(uint4*)(ab + ((ac0 ^ asw) << 4)) = ar0;
    *(uint4*)(ab + (((ac0 + 1) ^ asw) << 4)) = ar1;
  };

  f32x4 acc[4][4] = {};
  stageB(0, 0);
  loadA(0);
  storeA(0);
  __syncthreads();
  int cur = 0;
  for (int k0 = 0; k0 < 1024; k0 += 32) {
    const bool more = (k0 + 32) < 1024;
    if (more) {
      stageB(k0 + 32, cur ^ 1);
      loadA(k0 + 32);
    }
    const char* Ab = (const char*)&As[cur][0];
    const char* Bb = (const char*)&Bs[cur][0];
    FragU a[4], bf[4];
#pragma unroll
    for (int i = 0; i < 4; ++i) {
      const int rowa = wr + i * 16 + li;
      a[i].u = *(const uint4*)(Ab + rowa * 64 + (((g) ^ ((rowa >> 1) & 3)) << 4));
      const int rowb = wc + i * 16 + li;
      bf[i].u = *(const uint4*)(Bb + rowb * 64 + (((g) ^ ((rowb >> 1) & 3)) << 4));
    }
#pragma unroll
    for (int fm = 0; fm < 4; ++fm)
#pragma unroll
      for (int fn = 0; fn < 4; ++fn)
        acc[fm][fn] = __builtin_amdgcn_mfma_f32_16x16x32_bf16(a[fm].v, bf[fn].v, acc[fm][fn], 0, 0, 0);
    if (more) storeA(cur ^ 1);
    __syncthreads();
    cur ^= 1;
  }

  unsigned short* OutN = (z == 0) ? Qb : Kb;
#pragma unroll
  for (int fn = 0; fn < 4; ++fn) {
    const int n = n0 + wc + fn * 16 + li;
    const float bv2 = bias[n];
#pragma unroll
    for (int fm = 0; fm < 4; ++fm) {
      const int mb = m0 + wr + fm * 16 + g * 4;
      const f32x4 v = acc[fm][fn];
      ushort4 pk;
      pk.x = f2bf((v[0] + bv2) * scale);
      pk.y = f2bf((v[1] + bv2) * scale);
      pk.z = f2bf((v[2] + bv2) * scale);
      pk.w = f2bf((v[3] + bv2) * scale);
      if (z == 2) {
        const int bb = mb >> 11, s = mb & 2047;
        *(ushort4*)&Vt[(size_t)(bb * 1024 + n) * 2048 + s] = pk;
      } else {
        unsigned short* o = OutN;
        o[(size_t)(mb + 0) * 1024 + n] = pk.x;
        o[(size_t)(mb + 1) * 1024 + n] = pk.y;
        o[(size_t)(mb + 2) * 1024 + n] = pk.z;
        o[(size_t)(mb + 3) * 1024 + n] = pk.w;
      }
    }
  }
}

// ---------------- out GEMM: fp32 out = ctx(bf16) @ WoT^T + bo (3-buf counted vmcnt) -----
__global__ __launch_bounds__(256, 3) void out_gemm(const unsigned short* __restrict__ A,
                                                   const unsigned short* __restrict__ BT,
                                                   const float* __restrict__ bias,
                                                   float* __restrict__ Out) {
  __shared__ char AsB[3][8192];
  __shared__ char BsB[3][8192];
  const int t = threadIdx.x;
  const int lane = t & 63, w = t >> 6;
  const int g = lane >> 4, li = lane & 15;
  const int wr = (w >> 1) * 64, wc = (w & 1) * 64;
  const int lin = blockIdx.x + 8 * blockIdx.y;
  const int work = (lin & 7) * 32 + (lin >> 3);
  const int m0 = (work >> 3) * 128, n0 = (work & 7) * 128;

  const int r1 = t >> 2, c1 = (t & 3) ^ ((r1 >> 1) & 3);
  const int r2 = r1 + 64, c2 = (t & 3) ^ ((r2 >> 1) & 3);

  auto stage = [&](int kt, int buf) {
    const int k0 = kt * 32;
    gl_lds16(A + (size_t)(m0 + r1) * 1024 + k0 + c1 * 8, &AsB[buf][0] + (w << 10));
    gl_lds16(A + (size_t)(m0 + r2) * 1024 + k0 + c2 * 8, &AsB[buf][0] + 4096 + (w << 10));
    gl_lds16(BT + (size_t)(n0 + r1) * 1024 + k0 + c1 * 8, &BsB[buf][0] + (w << 10));
    gl_lds16(BT + (size_t)(n0 + r2) * 1024 + k0 + c2 * 8, &BsB[buf][0] + 4096 + (w << 10));
  };

  f32x4 acc[4][4] = {};
  stage(0, 0);
  stage(1, 1);
  asm volatile("s_waitcnt vmcnt(4)" ::: "memory");
  asm volatile("s_barrier" ::: "memory");

  int cur = 0;
  for (int kt = 0; kt < 32; ++kt) {
    if (kt < 30) {
      int nb = cur + 2; if (nb >= 3) nb -= 3;
      stage(kt + 2, nb);
    }
    const char* Ab = &AsB[cur][0];
    const char* Bb = &BsB[cur][0];
    FragU a[4], bf[4];
#pragma unroll
    for (int i = 0; i < 4; ++i) {
      const int ra = wr + i * 16 + li;
      a[i].u = *(const uint4*)(Ab + ra * 64 + ((g ^ ((ra >> 1) & 3)) << 4));
      const int rb = wc + i * 16 + li;
      bf[i].u = *(const uint4*)(Bb + rb * 64 + ((g ^ ((rb >> 1) & 3)) << 4));
    }
#pragma unroll
    for (int fm = 0; fm < 4; ++fm)
#pragma unroll
      for (int fn = 0; fn < 4; ++fn)
        acc[fm][fn] = __builtin_amdgcn_mfma_f32_16x16x32_bf16(a[fm].v, bf[fn].v, acc[fm][fn], 0, 0, 0);

    if (kt < 30) {
      asm volatile("s_waitcnt vmcnt(4)" ::: "memory");
    } else if (kt == 30) {
      asm volatile("s_waitcnt vmcnt(0)" ::: "memory");
    }
    if (kt < 31) asm volatile("s_barrier" ::: "memory");
    cur = (cur == 2) ? 0 : cur + 1;
  }

#pragma unroll
  for (int fn = 0; fn < 4; ++fn) {
    const int n = n0 + wc + fn * 16 + li;
    const float bv = bias[n];
#pragma unroll
    for (int fm = 0; fm < 4; ++fm) {
      const int mb = m0 + wr + fm * 16 + g * 4;
      const f32x4 v = acc[fm][fn];
#pragma unroll
      for (int r = 0; r < 4; ++r) Out[(size_t)(mb + r) * 1024 + n] = v[r] + bv;
    }
  }
}

// ---------------- flash attention: R9 geometry + dbuf global_load_lds staging ----------
// 512 blocks (XCD-swizzled), 4 waves x 32 q-rows, KV tile 64, NO parity split.
// Per iter: stage(i+1 -> buf^1) issued FIRST (DMA overlaps whole compute of buf),
// compute QK/softmax/PV from buf, then vmcnt(0) + one s_barrier, flip.
// K/V staged via gl_lds with pre-swizzled per-lane source s=(lane&7)^(lane>>3) so
// LDS holds the XOR-(row&7) layout the readers expect (validated in R11).
__global__ __launch_bounds__(256, 2) void attn_kernel(const unsigned short* __restrict__ Qb,
                                                      const unsigned short* __restrict__ Kb,
                                                      const unsigned short* __restrict__ Vt,
                                                      const int* __restrict__ mask,
                                                      unsigned short* __restrict__ ctx) {
  __shared__ char smem[2][16384];  // per buf: K 0..8K, V 8..16K
  const int t = threadIdx.x, lane = t & 63, w = t >> 6;
  const int l31 = lane & 31, hi = lane >> 5;
  const int d0 = blockIdx.x + 16 * blockIdx.y;
  const int work = (d0 & 7) * 64 + (d0 >> 3);
  const int qblk = work & 15, bh = work >> 4;
  const int b = bh >> 4, h = bh & 15;
  const int q0 = qblk * 128;
  const int qrow = b * 2048 + q0 + w * 32 + l31;

  const unsigned short* Kbase = Kb + (size_t)(b * 2048) * 1024 + h * 64;
  const unsigned short* Vbase = Vt + (size_t)(b * 1024 + h * 64) * 2048;

  const int srw = lane >> 3;          // 0..7
  const int ssc = (lane & 7) ^ srw;   // pre-swizzled source chunk (j-invariant)

  int mv_next;
  auto stage = [&](int i, int buf) {
    const int kv0 = i * 64;
#pragma unroll
    for (int j = 0; j < 2; ++j) {
      const int rr = w * 16 + j * 8 + srw;
      char* ldsb = &smem[buf][0] + w * 2048 + j * 1024;
      gl_lds16(Kbase + (size_t)(kv0 + rr) * 1024 + ssc * 8, ldsb);
      gl_lds16(Vbase + (size_t)rr * 2048 + kv0 + ssc * 8, ldsb + 8192);
    }
    mv_next = mask[b * 2048 + kv0 + lane];
  };

  FragU qf[4];
  {
    const unsigned short* qb = Qb + (size_t)qrow * 1024 + h * 64 + hi * 8;
#pragma unroll
    for (int dc = 0; dc < 4; ++dc) qf[dc].u = *(const uint4*)(qb + dc * 16);
  }

  stage(0, 0);
  asm volatile("s_waitcnt vmcnt(0)" ::: "memory");
  int mv_cur = mv_next;
  asm volatile("s_barrier" ::: "memory");
  __builtin_amdgcn_sched_barrier(0);

  f32x16 acc[2] = {};
  float m_run = 8.0f, l_run = 0.f;
  int cur = 0;

  for (int i = 0; i < 32; ++i) {
    if (i < 31) stage(i + 1, cur ^ 1);  // DMA runs during the whole compute below
    const int mvcur = mv_cur;
    const char* Ksp = &smem[cur][0];
    const char* Vsp = &smem[cur][8192];

    // QK^T
    f32x16 sc[2] = {};
    {
      __builtin_amdgcn_s_setprio(1);
#pragma unroll
      for (int t2 = 0; t2 < 2; ++t2) {
        const int row = t2 * 32 + l31;
        const int sw = (row & 7) << 4;
        const int rb = row * 128;
#pragma unroll
        for (int dc = 0; dc < 4; ++dc) {
          FragU kf;
          kf.u = *(const uint4*)(Ksp + rb + ((16 * (dc * 2 + hi)) ^ sw));
          sc[t2] = __builtin_amdgcn_mfma_f32_32x32x16_bf16(kf.v, qf[dc].v, sc[t2], 0, 0, 0);
        }
      }
      __builtin_amdgcn_s_setprio(0);
    }

    if (!__all(mvcur != 0)) {
#pragma unroll
      for (int t2 = 0; t2 < 2; ++t2)
#pragma unroll
        for (int r = 0; r < 16; ++r) {
          const int kvv = t2 * 32 + (r & 3) + 8 * (r >> 2) + 4 * hi;
          sc[t2][r] += (__shfl(mvcur, kvv, 64) ? 0.f : -30000.f);
        }
    }

    float pm = sc[0][0];
#pragma unroll
    for (int t2 = 0; t2 < 2; ++t2)
#pragma unroll
      for (int r = 0; r < 16; ++r) pm = fmaxf(pm, sc[t2][r]);
    pm = fmaxf(pm, __shfl_xor(pm, 32, 64));

    if (!__all(pm <= m_run + 8.f)) {
      const float m_new = fmaxf(m_run, pm);
      const float rsc = __builtin_amdgcn_exp2f(m_run - m_new);
      m_run = m_new;
      l_run *= rsc;
#pragma unroll
      for (int dt = 0; dt < 2; ++dt)
#pragma unroll
        for (int r = 0; r < 16; ++r) acc[dt][r] *= rsc;
    }

    float rs = 0.f;
#pragma unroll
    for (int t2 = 0; t2 < 2; ++t2)
#pragma unroll
      for (int r = 0; r < 16; ++r) {
        const float e = __builtin_amdgcn_exp2f(sc[t2][r] - m_run);
        sc[t2][r] = e;
        rs += e;
      }
    l_run += rs;

    FragU pf[4];
#pragma unroll
    for (int ks = 0; ks < 4; ++ks) {
      const int t2 = ks >> 1, s8 = (ks & 1) * 8;
      uint32_t U = pk2bf(sc[t2][s8 + 0], sc[t2][s8 + 1]);
      uint32_t V2 = pk2bf(sc[t2][s8 + 2], sc[t2][s8 + 3]);
      uint32_t X = pk2bf(sc[t2][s8 + 4], sc[t2][s8 + 5]);
      uint32_t Y = pk2bf(sc[t2][s8 + 6], sc[t2][s8 + 7]);
      asm("v_permlane32_swap_b32 %0, %1" : "+v"(U), "+v"(X));
      asm("v_permlane32_swap_b32 %0, %1" : "+v"(V2), "+v"(Y));
      pf[ks].u = uint4{U, V2, X, Y};
    }

    // PV
    {
      __builtin_amdgcn_s_setprio(1);
#pragma unroll
      for (int dt = 0; dt < 2; ++dt) {
        const int drow = dt * 32 + l31;
        const int sw = (drow & 7) << 4;
        const int rb = drow * 128;
#pragma unroll
        for (int ks = 0; ks < 4; ++ks) {
          FragU vf;
          vf.u = *(const uint4*)(Vsp + rb + ((16 * (ks * 2 + hi)) ^ sw));
          acc[dt] = __builtin_amdgcn_mfma_f32_32x32x16_bf16(vf.v, pf[ks].v, acc[dt], 0, 0, 0);
        }
      }
      __builtin_amdgcn_s_setprio(0);
    }

    if (i < 31) {
      asm volatile("s_waitcnt vmcnt(0)" ::: "memory");  // stage(i+1) done (hid under compute)
      mv_cur = mv_next;
      asm volatile("s_barrier" ::: "memory");           // reads of cur done; writes visible
      __builtin_amdgcn_sched_barrier(0);
      cur ^= 1;
    }
  }

  const float l_tot = l_run + __shfl_xor(l_run, 32, 64);
  const float inv_l = 1.0f / l_tot;
  unsigned short* cb = ctx + (size_t)qrow * 1024 + h * 64;
#pragma unroll
  for (int dt = 0; dt < 2; ++dt)
#pragma unroll
    for (int rq = 0; rq < 4; ++rq) {
      uint2 o;
      o.x = pk2bf(acc[dt][rq * 4 + 0] * inv_l, acc[dt][rq * 4 + 1] * inv_l);
      o.y = pk2bf(acc[dt][rq * 4 + 2] * inv_l, acc[dt][rq * 4 + 3] * inv_l);
      *(uint2*)(cb + dt * 32 + rq * 8 + hi * 4) = o;
    }
}

extern "C" void kernel_launch(void* const* d_in, const int* in_sizes, int n_in,
                              void* d_out, int out_size, void* d_ws, size_t ws_size,
                              hipStream_t stream) {
  const float* query = (const float*)d_in[0];
  const float* key = (const float*)d_in[1];
  const float* value = (const float*)d_in[2];
  const int* mask = (const int*)d_in[3];
  const float* Wq = (const float*)d_in[4];
  const float* bq = (const float*)d_in[5];
  const float* Wk = (const float*)d_in[6];
  const float* bk = (const float*)d_in[7];
  const float* Wv = (const float*)d_in[8];
  const float* bv = (const float*)d_in[9];
  const float* Wo = (const float*)d_in[10];
  const float* bo = (const float*)d_in[11];
  float* out = (float*)d_out;

  const size_t MB = 1024 * 1024;
  if (ws_size < 40 * MB) return;
  char* ws = (char*)d_ws;
  unsigned short* WqT = (unsigned short*)(ws);
  unsigned short* WkT = (unsigned short*)(ws + 2 * MB);
  unsigned short* WvT = (unsigned short*)(ws + 4 * MB);
  unsigned short* WoT = (unsigned short*)(ws + 6 * MB);
  unsigned short* Qb = (unsigned short*)(ws + 8 * MB);
  unsigned short* Kb = (unsigned short*)(ws + 16 * MB);
  unsigned short* Vt = (unsigned short*)(ws + 24 * MB);
  unsigned short* ctx = (unsigned short*)(ws + 32 * MB);

  const dim3 tb(256);
  const float qscale = 0.125f * 1.4426950408889634f;

  if (ws_size >= 64 * MB) {
    unsigned short* Qc = (unsigned short*)(ws + 40 * MB);
    unsigned short* Kc = (unsigned short*)(ws + 48 * MB);
    unsigned short* Vc = (unsigned short*)(ws + 56 * MB);
    prep_kernel<<<dim3(7168), tb, 0, stream>>>(Wq, Wk, Wv, Wo, WqT, WkT, WvT, WoT,
                                               query, key, value, Qc, Kc, Vc);
    qkv_gemm_bf16<<<dim3(8, 32, 3), tb, 0, stream>>>(Qc, Kc, Vc, WqT, WkT, WvT,
                                                     bq, bk, bv, Qb, Kb, Vt, qscale);
  } else {
    wt4_kernel<<<dim3(16, 16, 4), tb, 0, stream>>>(Wq, Wk, Wv, Wo, WqT, WkT, WvT, WoT);
    qkv_gemm_f32<<<dim3(8, 32, 3), tb, 0, stream>>>(query, key, value, WqT, WkT, WvT,
                                                    bq, bk, bv, Qb, Kb, Vt, qscale);
  }

  attn_kernel<<<dim3(16, 32), tb, 0, stream>>>(Qb, Kb, Vt, mask, ctx);

  out_gemm<<<dim3(8, 32), tb, 0, stream>>>(ctx, WoT, bo, out);
}

// Round 14
// 122.391 us; speedup vs baseline: 1.8397x; 1.0219x over previous
//
#include <hip/hip_runtime.h>
#include <hip/hip_bf16.h>
#include <stdint.h>

typedef short s16x8 __attribute__((ext_vector_type(8)));
typedef float f32x4 __attribute__((ext_vector_type(4)));
typedef float f32x16 __attribute__((ext_vector_type(16)));

union FragU { uint4 u; s16x8 v; };

static __device__ __forceinline__ uint32_t pk2bf(float a, float b) {
  union { __hip_bfloat162 h; uint32_t u; } cv;
  cv.h = __float22bfloat162_rn(make_float2(a, b));
  return cv.u;
}

static __device__ __forceinline__ unsigned short f2bf(float f) {
  union { float f; uint32_t u; } x; x.f = f;
  uint32_t r = x.u + 0x7FFFu + ((x.u >> 16) & 1u);  // RNE
  return (unsigned short)(r >> 16);
}

static __device__ __forceinline__ void gl_lds16(const void* g, void* lds_wave_base) {
  __builtin_amdgcn_global_load_lds(
      (const __attribute__((address_space(1))) uint32_t*)(uintptr_t)g,
      (__attribute__((address_space(3))) uint32_t*)(uintptr_t)lds_wave_base, 16, 0, 0);
}

// ---------------- prep: 4x weight transpose (blocks 0-1023) + qkv fp32->bf16 cvt ----------
__global__ __launch_bounds__(256) void prep_kernel(const float* __restrict__ W0,
                                                   const float* __restrict__ W1,
                                                   const float* __restrict__ W2,
                                                   const float* __restrict__ W3,
                                                   unsigned short* __restrict__ T0,
                                                   unsigned short* __restrict__ T1,
                                                   unsigned short* __restrict__ T2,
                                                   unsigned short* __restrict__ T3,
                                                   const float* __restrict__ qs,
                                                   const float* __restrict__ ks,
                                                   const float* __restrict__ vs,
                                                   unsigned short* __restrict__ Qc,
                                                   unsigned short* __restrict__ Kc,
                                                   unsigned short* __restrict__ Vc) {
  __shared__ unsigned short tile[64][68];
  const int blk = blockIdx.x;
  const int t = threadIdx.x;
  if (blk < 1024) {
    const int z = blk >> 8;
    const float* W = (z == 0) ? W0 : (z == 1) ? W1 : (z == 2) ? W2 : W3;
    unsigned short* WT = (z == 0) ? T0 : (z == 1) ? T1 : (z == 2) ? T2 : T3;
    const int n0 = (blk & 15) * 64, k0 = ((blk >> 4) & 15) * 64;
    const int r = t >> 4, c4 = (t & 15) * 4;
#pragma unroll
    for (int i = 0; i < 4; ++i) {
      const int k = i * 16 + r;
      const float4 v = *(const float4*)&W[(k0 + k) * 1024 + n0 + c4];
      tile[k][c4 + 0] = f2bf(v.x);
      tile[k][c4 + 1] = f2bf(v.y);
      tile[k][c4 + 2] = f2bf(v.z);
      tile[k][c4 + 3] = f2bf(v.w);
    }
    __syncthreads();
#pragma unroll
    for (int i = 0; i < 4; ++i) {
      const int n = i * 16 + r;
      ushort4 o;
      o.x = tile[c4 + 0][n];
      o.y = tile[c4 + 1][n];
      o.z = tile[c4 + 2][n];
      o.w = tile[c4 + 3][n];
      *(ushort4*)&WT[(n0 + n) * 1024 + k0 + c4] = o;
    }
  } else {
    const int c = blk - 1024;  // 0..6143
    const int z = c >> 11, sub = c & 2047;
    const float* src = (z == 0) ? qs : (z == 1) ? ks : vs;
    unsigned short* dst = (z == 0) ? Qc : (z == 1) ? Kc : Vc;
    const size_t base = ((size_t)sub * 256 + t) * 8;
    const float4 f0 = *(const float4*)(src + base);
    const float4 f1 = *(const float4*)(src + base + 4);
    const uint4 o{pk2bf(f0.x, f0.y), pk2bf(f0.z, f0.w), pk2bf(f1.x, f1.y), pk2bf(f1.z, f1.w)};
    *(uint4*)(dst + base) = o;
  }
}

// legacy wt-only (fallback path when ws too small for cvt buffers)
__global__ __launch_bounds__(256) void wt4_kernel(const float* __restrict__ W0,
                                                  const float* __restrict__ W1,
                                                  const float* __restrict__ W2,
                                                  const float* __restrict__ W3,
                                                  unsigned short* __restrict__ T0,
                                                  unsigned short* __restrict__ T1,
                                                  unsigned short* __restrict__ T2,
                                                  unsigned short* __restrict__ T3) {
  __shared__ unsigned short tile[64][68];
  const int z = blockIdx.z;
  const float* W = (z == 0) ? W0 : (z == 1) ? W1 : (z == 2) ? W2 : W3;
  unsigned short* WT = (z == 0) ? T0 : (z == 1) ? T1 : (z == 2) ? T2 : T3;
  const int t = threadIdx.x;
  const int n0 = blockIdx.x * 64, k0 = blockIdx.y * 64;
  const int r = t >> 4, c4 = (t & 15) * 4;
#pragma unroll
  for (int i = 0; i < 4; ++i) {
    const int k = i * 16 + r;
    const float4 v = *(const float4*)&W[(k0 + k) * 1024 + n0 + c4];
    tile[k][c4 + 0] = f2bf(v.x);
    tile[k][c4 + 1] = f2bf(v.y);
    tile[k][c4 + 2] = f2bf(v.z);
    tile[k][c4 + 3] = f2bf(v.w);
  }
  __syncthreads();
#pragma unroll
  for (int i = 0; i < 4; ++i) {
    const int n = i * 16 + r;
    ushort4 o;
    o.x = tile[c4 + 0][n];
    o.y = tile[c4 + 1][n];
    o.z = tile[c4 + 2][n];
    o.w = tile[c4 + 3][n];
    *(ushort4*)&WT[(n0 + n) * 1024 + k0 + c4] = o;
  }
}

// ---------------- fused QKV GEMM, all-bf16, 3-buf counted-vmcnt pipeline ----------------
__global__ __launch_bounds__(256, 3) void qkv_gemm_bf16(const unsigned short* __restrict__ Aq,
                                                        const unsigned short* __restrict__ Ak,
                                                        const unsigned short* __restrict__ Av,
                                                        const unsigned short* __restrict__ Wq,
                                                        const unsigned short* __restrict__ Wk,
                                                        const unsigned short* __restrict__ Wv,
                                                        const float* __restrict__ bq,
                                                        const float* __restrict__ bk,
                                                        const float* __restrict__ bv,
                                                        unsigned short* __restrict__ Qb,
                                                        unsigned short* __restrict__ Kb,
                                                        unsigned short* __restrict__ Vt,
                                                        const float qscale) {
  __shared__ char AsB[3][8192];
  __shared__ char BsB[3][8192];
  const int t = threadIdx.x;
  const int z = blockIdx.z;
  const unsigned short* A = (z == 0) ? Aq : (z == 1) ? Ak : Av;
  const unsigned short* BT = (z == 0) ? Wq : (z == 1) ? Wk : Wv;
  const float* bias = (z == 0) ? bq : (z == 1) ? bk : bv;
  const float scale = (z == 0) ? qscale : 1.0f;

  const int lane = t & 63, w = t >> 6;
  const int g = lane >> 4, li = lane & 15;
  const int wr = (w >> 1) * 64, wc = (w & 1) * 64;
  const int lin = blockIdx.x + 8 * blockIdx.y;
  const int work = (lin & 7) * 32 + (lin >> 3);
  const int m0 = (work >> 3) * 128, n0 = (work & 7) * 128;

  const int r1 = t >> 2, c1 = (t & 3) ^ ((r1 >> 1) & 3);
  const int r2 = r1 + 64, c2 = (t & 3) ^ ((r2 >> 1) & 3);

  auto stage = [&](int kt, int buf) {
    const int k0 = kt * 32;
    gl_lds16(A + (size_t)(m0 + r1) * 1024 + k0 + c1 * 8, &AsB[buf][0] + (w << 10));
    gl_lds16(A + (size_t)(m0 + r2) * 1024 + k0 + c2 * 8, &AsB[buf][0] + 4096 + (w << 10));
    gl_lds16(BT + (size_t)(n0 + r1) * 1024 + k0 + c1 * 8, &BsB[buf][0] + (w << 10));
    gl_lds16(BT + (size_t)(n0 + r2) * 1024 + k0 + c2 * 8, &BsB[buf][0] + 4096 + (w << 10));
  };

  f32x4 acc[4][4] = {};
  stage(0, 0);
  stage(1, 1);
  asm volatile("s_waitcnt vmcnt(4)" ::: "memory");
  asm volatile("s_barrier" ::: "memory");

  int cur = 0;
  for (int kt = 0; kt < 32; ++kt) {
    if (kt < 30) {
      int nb = cur + 2; if (nb >= 3) nb -= 3;
      stage(kt + 2, nb);
    }
    const char* Ab = &AsB[cur][0];
    const char* Bb = &BsB[cur][0];
    FragU a[4], bf[4];
#pragma unroll
    for (int i = 0; i < 4; ++i) {
      const int ra = wr + i * 16 + li;
      a[i].u = *(const uint4*)(Ab + ra * 64 + ((g ^ ((ra >> 1) & 3)) << 4));
      const int rb = wc + i * 16 + li;
      bf[i].u = *(const uint4*)(Bb + rb * 64 + ((g ^ ((rb >> 1) & 3)) << 4));
    }
#pragma unroll
    for (int fm = 0; fm < 4; ++fm)
#pragma unroll
      for (int fn = 0; fn < 4; ++fn)
        acc[fm][fn] = __builtin_amdgcn_mfma_f32_16x16x32_bf16(a[fm].v, bf[fn].v, acc[fm][fn], 0, 0, 0);

    if (kt < 30) {
      asm volatile("s_waitcnt vmcnt(4)" ::: "memory");
    } else if (kt == 30) {
      asm volatile("s_waitcnt vmcnt(0)" ::: "memory");
    }
    if (kt < 31) asm volatile("s_barrier" ::: "memory");
    cur = (cur == 2) ? 0 : cur + 1;
  }

  unsigned short* OutN = (z == 0) ? Qb : Kb;
#pragma unroll
  for (int fn = 0; fn < 4; ++fn) {
    const int n = n0 + wc + fn * 16 + li;
    const float bv2 = bias[n];
#pragma unroll
    for (int fm = 0; fm < 4; ++fm) {
      const int mb = m0 + wr + fm * 16 + g * 4;
      const f32x4 v = acc[fm][fn];
      ushort4 pk;
      pk.x = f2bf((v[0] + bv2) * scale);
      pk.y = f2bf((v[1] + bv2) * scale);
      pk.z = f2bf((v[2] + bv2) * scale);
      pk.w = f2bf((v[3] + bv2) * scale);
      if (z == 2) {
        const int bb = mb >> 11, s = mb & 2047;
        *(ushort4*)&Vt[(size_t)(bb * 1024 + n) * 2048 + s] = pk;
      } else {
        unsigned short* o = OutN;
        o[(size_t)(mb + 0) * 1024 + n] = pk.x;
        o[(size_t)(mb + 1) * 1024 + n] = pk.y;
        o[(size_t)(mb + 2) * 1024 + n] = pk.z;
        o[(size_t)(mb + 3) * 1024 + n] = pk.w;
      }
    }
  }
}

// ---------------- fallback fused QKV GEMM (fp32 A reg-convert, 2-buf) -------------------
__global__ __launch_bounds__(256, 3) void qkv_gemm_f32(const float* __restrict__ Aq,
                                                       const float* __restrict__ Ak,
                                                       const float* __restrict__ Av,
                                                       const unsigned short* __restrict__ Wq,
                                                       const unsigned short* __restrict__ Wk,
                                                       const unsigned short* __restrict__ Wv,
                                                       const float* __restrict__ bq,
                                                       const float* __restrict__ bk,
                                                       const float* __restrict__ bv,
                                                       unsigned short* __restrict__ Qb,
                                                       unsigned short* __restrict__ Kb,
                                                       unsigned short* __restrict__ Vt,
                                                       const float qscale) {
  __shared__ unsigned short As[2][128 * 32];
  __shared__ unsigned short Bs[2][128 * 32];
  const int t = threadIdx.x;
  const int z = blockIdx.z;
  const float* A = (z == 0) ? Aq : (z == 1) ? Ak : Av;
  const unsigned short* BT = (z == 0) ? Wq : (z == 1) ? Wk : Wv;
  const float* bias = (z == 0) ? bq : (z == 1) ? bk : bv;
  const float scale = (z == 0) ? qscale : 1.0f;

  const int lane = t & 63, w = t >> 6;
  const int g = lane >> 4, li = lane & 15;
  const int wr = (w >> 1) * 64, wc = (w & 1) * 64;
  const int lin = blockIdx.x + 8 * blockIdx.y;
  const int work = (lin & 7) * 32 + (lin >> 3);
  const int m0 = (work >> 3) * 128, n0 = (work & 7) * 128;

  const int arow = t >> 1, ac0 = (t & 1) * 2, asw = (arow >> 1) & 3;
  const int br1 = t >> 2, bg1 = (t & 3) ^ ((br1 >> 1) & 3);
  const int br2 = br1 + 64, bg2 = (t & 3) ^ ((br2 >> 1) & 3);

  auto stageB = [&](int k0, int buf) {
    gl_lds16(BT + (size_t)(n0 + br1) * 1024 + k0 + bg1 * 8, (char*)&Bs[buf][0] + (w << 10));
    gl_lds16(BT + (size_t)(n0 + br2) * 1024 + k0 + bg2 * 8, (char*)&Bs[buf][0] + 4096 + (w << 10));
  };

  uint4 ar0, ar1;
  auto loadA = [&](int k0) {
    const float* ga = A + (size_t)(m0 + arow) * 1024 + k0 + ac0 * 8;
    const float4 f0 = *(const float4*)(ga + 0), f1 = *(const float4*)(ga + 4);
    const float4 f2 = *(const float4*)(ga + 8), f3 = *(const float4*)(ga + 12);
    ar0 = uint4{pk2bf(f0.x, f0.y), pk2bf(f0.z, f0.w), pk2bf(f1.x, f1.y), pk2bf(f1.z, f1.w)};
    ar1 = uint4{pk2bf(f2.x, f2.y), pk2bf(f2.z, f2.w), pk2bf(f3.x, f3.y), pk2bf(f3.z, f3.w)};
  };
  auto storeA = [&](int buf) {
    char* ab = (char*)&As[buf][0] + arow * 64;
    *(uint4*)(ab + ((ac0 ^ asw) << 4)) = ar0;
    *(uint4*)(ab + (((ac0 + 1) ^ asw) << 4)) = ar1;
  };

  f32x4 acc[4][4] = {};
  stageB(0, 0);
  loadA(0);
  storeA(0);
  __syncthreads();
  int cur = 0;
  for (int k0 = 0; k0 < 1024; k0 += 32) {
    const bool more = (k0 + 32) < 1024;
    if (more) {
      stageB(k0 + 32, cur ^ 1);
      loadA(k0 + 32);
    }
    const char* Ab = (const char*)&As[cur][0];
    const char* Bb = (const char*)&Bs[cur][0];
    FragU a[4], bf[4];
#pragma unroll
    for (int i = 0; i < 4; ++i) {
      const int rowa = wr + i * 16 + li;
      a[i].u = *(const uint4*)(Ab + rowa * 64 + (((g) ^ ((rowa >> 1) & 3)) << 4));
      const int rowb = wc + i * 16 + li;
      bf[i].u = *(const uint4*)(Bb + rowb * 64 + (((g) ^ ((rowb >> 1) & 3)) << 4));
    }
#pragma unroll
    for (int fm = 0; fm < 4; ++fm)
#pragma unroll
      for (int fn = 0; fn < 4; ++fn)
        acc[fm][fn] = __builtin_amdgcn_mfma_f32_16x16x32_bf16(a[fm].v, bf[fn].v, acc[fm][fn], 0, 0, 0);
    if (more) storeA(cur ^ 1);
    __syncthreads();
    cur ^= 1;
  }

  unsigned short* OutN = (z == 0) ? Qb : Kb;
#pragma unroll
  for (int fn = 0; fn < 4; ++fn) {
    const int n = n0 + wc + fn * 16 + li;
    const float bv2 = bias[n];
#pragma unroll
    for (int fm = 0; fm < 4; ++fm) {
      const int mb = m0 + wr + fm * 16 + g * 4;
      const f32x4 v = acc[fm][fn];
      ushort4 pk;
      pk.x = f2bf((v[0] + bv2) * scale);
      pk.y = f2bf((v[1] + bv2) * scale);
      pk.z = f2bf((v[2] + bv2) * scale);
      pk.w = f2bf((v[3] + bv2) * scale);
      if (z == 2) {
        const int bb = mb >> 11, s = mb & 2047;
        *(ushort4*)&Vt[(size_t)(bb * 1024 + n) * 2048 + s] = pk;
      } else {
        unsigned short* o = OutN;
        o[(size_t)(mb + 0) * 1024 + n] = pk.x;
        o[(size_t)(mb + 1) * 1024 + n] = pk.y;
        o[(size_t)(mb + 2) * 1024 + n] = pk.z;
        o[(size_t)(mb + 3) * 1024 + n] = pk.w;
      }
    }
  }
}

// ---------------- out GEMM: fp32 out = ctx(bf16) @ WoT^T + bo ----------------
// BM=128, BN=64 -> 512 blocks (2/CU). 3-buf counted vmcnt(3). 4 waves (2m x 2n), 4x2 frags.
__global__ __launch_bounds__(256, 3) void out_gemm(const unsigned short* __restrict__ A,
                                                   const unsigned short* __restrict__ BT,
                                                   const float* __restrict__ bias,
                                                   float* __restrict__ Out) {
  __shared__ char AsB[3][8192];
  __shared__ char BsB[3][4096];
  const int t = threadIdx.x;
  const int lane = t & 63, w = t >> 6;
  const int g = lane >> 4, li = lane & 15;
  const int wr = (w >> 1) * 64, wc = (w & 1) * 32;
  const int lin = blockIdx.x + 16 * blockIdx.y;        // grid (16,32) = 512
  const int work = (lin & 7) * 64 + (lin >> 3);        // XCD-contiguous
  const int m0 = (work >> 4) * 128, n0 = (work & 15) * 64;

  const int r1 = t >> 2, c1 = (t & 3) ^ ((r1 >> 1) & 3);
  const int r2 = r1 + 64, c2 = (t & 3) ^ ((r2 >> 1) & 3);

  auto stage = [&](int kt, int buf) {
    const int k0 = kt * 32;
    gl_lds16(A + (size_t)(m0 + r1) * 1024 + k0 + c1 * 8, &AsB[buf][0] + (w << 10));
    gl_lds16(A + (size_t)(m0 + r2) * 1024 + k0 + c2 * 8, &AsB[buf][0] + 4096 + (w << 10));
    gl_lds16(BT + (size_t)(n0 + r1) * 1024 + k0 + c1 * 8, &BsB[buf][0] + (w << 10));
  };

  f32x4 acc[4][2] = {};
  stage(0, 0);
  stage(1, 1);
  asm volatile("s_waitcnt vmcnt(3)" ::: "memory");
  asm volatile("s_barrier" ::: "memory");

  int cur = 0;
  for (int kt = 0; kt < 32; ++kt) {
    if (kt < 30) {
      int nb = cur + 2; if (nb >= 3) nb -= 3;
      stage(kt + 2, nb);
    }
    const char* Ab = &AsB[cur][0];
    const char* Bb = &BsB[cur][0];
    FragU a[4], bf[2];
#pragma unroll
    for (int i = 0; i < 4; ++i) {
      const int ra = wr + i * 16 + li;
      a[i].u = *(const uint4*)(Ab + ra * 64 + ((g ^ ((ra >> 1) & 3)) << 4));
    }
#pragma unroll
    for (int j = 0; j < 2; ++j) {
      const int rb = wc + j * 16 + li;
      bf[j].u = *(const uint4*)(Bb + rb * 64 + ((g ^ ((rb >> 1) & 3)) << 4));
    }
#pragma unroll
    for (int fm = 0; fm < 4; ++fm)
#pragma unroll
      for (int fn = 0; fn < 2; ++fn)
        acc[fm][fn] = __builtin_amdgcn_mfma_f32_16x16x32_bf16(a[fm].v, bf[fn].v, acc[fm][fn], 0, 0, 0);

    if (kt < 30) {
      asm volatile("s_waitcnt vmcnt(3)" ::: "memory");
    } else if (kt == 30) {
      asm volatile("s_waitcnt vmcnt(0)" ::: "memory");
    }
    if (kt < 31) asm volatile("s_barrier" ::: "memory");
    cur = (cur == 2) ? 0 : cur + 1;
  }

#pragma unroll
  for (int fn = 0; fn < 2; ++fn) {
    const int n = n0 + wc + fn * 16 + li;
    const float bv = bias[n];
#pragma unroll
    for (int fm = 0; fm < 4; ++fm) {
      const int mb = m0 + wr + fm * 16 + g * 4;
      const f32x4 v = acc[fm][fn];
#pragma unroll
      for (int r = 0; r < 4; ++r) Out[(size_t)(mb + r) * 1024 + n] = v[r] + bv;
    }
  }
}

// ---------------- flash attention: R9 base + T15 two-tile pipeline, 3 LDS buffers -------
// 512 blocks (XCD-swizzled), 4 waves x 32 q-rows, KV tile 64. Tile i lives in buf(i%3).
// Per step: QK(i+1) [MFMA] || softmax(i) [VALU] overlap; PV(i); storeKV(i+2 -> free buf);
// loadKV(i+3) -> regs; one __syncthreads. Reg-staged K/V (R9-proven), XOR-(row&7) LDS.
// R14 fix: PV must read the V HALF of the buffer (base + 8192) — R13 passed the K half.
__global__ __launch_bounds__(256, 2) void attn_kernel(const unsigned short* __restrict__ Qb,
                                                      const unsigned short* __restrict__ Kb,
                                                      const unsigned short* __restrict__ Vt,
                                                      const int* __restrict__ mask,
                                                      unsigned short* __restrict__ ctx) {
  __shared__ char smem[3][16384];  // per buf: K 0..8K, V 8..16K
  const int t = threadIdx.x, lane = t & 63, w = t >> 6;
  const int l31 = lane & 31, hi = lane >> 5;
  const int d0 = blockIdx.x + 16 * blockIdx.y;
  const int work = (d0 & 7) * 64 + (d0 >> 3);
  const int qblk = work & 15, bh = work >> 4;
  const int b = bh >> 4, h = bh & 15;
  const int q0 = qblk * 128;
  const int qrow = b * 2048 + q0 + w * 32 + l31;

  const int srow = t >> 3, sch = t & 7;

  const unsigned short* Kbase = Kb + (size_t)(b * 2048) * 1024 + h * 64;
  const unsigned short* Vbase = Vt + (size_t)(b * 1024 + h * 64) * 2048;
  const int* mbase = mask + b * 2048 + lane;

  uint4 kr0, kr1, vr0, vr1;
  auto loadKV = [&](int i) {
    const int kvn = i * 64;
    kr0 = *(const uint4*)(Kbase + (size_t)(kvn + srow) * 1024 + sch * 8);
    kr1 = *(const uint4*)(Kbase + (size_t)(kvn + srow + 32) * 1024 + sch * 8);
    vr0 = *(const uint4*)(Vbase + (size_t)srow * 2048 + kvn + sch * 8);
    vr1 = *(const uint4*)(Vbase + (size_t)(srow + 32) * 2048 + kvn + sch * 8);
  };
  auto storeKV = [&](char* bufp) {
    char* kb = bufp;
    char* vb = bufp + 8192;
    const int o0 = srow * 128 + ((sch * 16) ^ ((srow & 7) << 4));
    const int o1 = (srow + 32) * 128 + ((sch * 16) ^ ((srow & 7) << 4));
    *(uint4*)(kb + o0) = kr0;
    *(uint4*)(kb + o1) = kr1;
    *(uint4*)(vb + o0) = vr0;
    *(uint4*)(vb + o1) = vr1;
  };

  FragU qf[4];
  {
    const unsigned short* qb = Qb + (size_t)qrow * 1024 + h * 64 + hi * 8;
#pragma unroll
    for (int dc = 0; dc < 4; ++dc) qf[dc].u = *(const uint4*)(qb + dc * 16);
  }

  f32x16 acc[2] = {};
  float m_run = 8.0f, l_run = 0.f;

  // QK(tile at kb) -> sc
  auto QK = [&](f32x16 (&sc)[2], const char* kb) {
#pragma unroll
    for (int r = 0; r < 16; ++r) { sc[0][r] = 0.f; sc[1][r] = 0.f; }
    __builtin_amdgcn_s_setprio(1);
#pragma unroll
    for (int t2 = 0; t2 < 2; ++t2) {
      const int row = t2 * 32 + l31;
      const int sw = (row & 7) << 4;
      const int rb = row * 128;
#pragma unroll
      for (int dc = 0; dc < 4; ++dc) {
        FragU kf;
        kf.u = *(const uint4*)(kb + rb + ((16 * (dc * 2 + hi)) ^ sw));
        sc[t2] = __builtin_amdgcn_mfma_f32_32x32x16_bf16(kf.v, qf[dc].v, sc[t2], 0, 0, 0);
      }
    }
    __builtin_amdgcn_s_setprio(0);
  };

  // softmax(sc) + PV from vb (vb = V half pointer!)
  auto SOFTPV = [&](f32x16 (&sc)[2], int mvcur, const char* vb) {
    if (!__all(mvcur != 0)) {
#pragma unroll
      for (int t2 = 0; t2 < 2; ++t2)
#pragma unroll
        for (int r = 0; r < 16; ++r) {
          const int kvv = t2 * 32 + (r & 3) + 8 * (r >> 2) + 4 * hi;
          sc[t2][r] += (__shfl(mvcur, kvv, 64) ? 0.f : -30000.f);
        }
    }

    float pm = sc[0][0];
#pragma unroll
    for (int t2 = 0; t2 < 2; ++t2)
#pragma unroll
      for (int r = 0; r < 16; ++r) pm = fmaxf(pm, sc[t2][r]);
    pm = fmaxf(pm, __shfl_xor(pm, 32, 64));

    if (!__all(pm <= m_run + 8.f)) {
      const float m_new = fmaxf(m_run, pm);
      const float rsc = __builtin_amdgcn_exp2f(m_run - m_new);
      m_run = m_new;
      l_run *= rsc;
#pragma unroll
      for (int dt = 0; dt < 2; ++dt)
#pragma unroll
        for (int r = 0; r < 16; ++r) acc[dt][r] *= rsc;
    }

    float rs = 0.f;
#pragma unroll
    for (int t2 = 0; t2 < 2; ++t2)
#pragma unroll
      for (int r = 0; r < 16; ++r) {
        const float e = __builtin_amdgcn_exp2f(sc[t2][r] - m_run);
        sc[t2][r] = e;
        rs += e;
      }
    l_run += rs;

    FragU pf[4];
#pragma unroll
    for (int ks = 0; ks < 4; ++ks) {
      const int t2 = ks >> 1, s8 = (ks & 1) * 8;
      uint32_t U = pk2bf(sc[t2][s8 + 0], sc[t2][s8 + 1]);
      uint32_t V2 = pk2bf(sc[t2][s8 + 2], sc[t2][s8 + 3]);
      uint32_t X = pk2bf(sc[t2][s8 + 4], sc[t2][s8 + 5]);
      uint32_t Y = pk2bf(sc[t2][s8 + 6], sc[t2][s8 + 7]);
      asm("v_permlane32_swap_b32 %0, %1" : "+v"(U), "+v"(X));
      asm("v_permlane32_swap_b32 %0, %1" : "+v"(V2), "+v"(Y));
      pf[ks].u = uint4{U, V2, X, Y};
    }

    __builtin_amdgcn_s_setprio(1);
#pragma unroll
    for (int dt = 0; dt < 2; ++dt) {
      const int drow = dt * 32 + l31;
      const int sw = (drow & 7) << 4;
      const int rb = drow * 128;
#pragma unroll
      for (int ks = 0; ks < 4; ++ks) {
        FragU vf;
        vf.u = *(const uint4*)(vb + rb + ((16 * (ks * 2 + hi)) ^ sw));
        acc[dt] = __builtin_amdgcn_mfma_f32_32x32x16_bf16(vf.v, pf[ks].v, acc[dt], 0, 0, 0);
      }
    }
    __builtin_amdgcn_s_setprio(0);
  };

  // prologue: tiles 0,1 into bufs 0,1; tile 2 in regs
  loadKV(0); storeKV(&smem[0][0]);
  loadKV(1); storeKV(&smem[1][0]);
  loadKV(2);
  __syncthreads();

  char* bE = &smem[0][0];
  char* bO = &smem[1][0];
  char* bN = &smem[2][0];

  f32x16 scA[2], scB[2];
  QK(scA, bE);  // tile 0

  for (int k = 0; k < 15; ++k) {
    // step A: tile e = 2k
    {
      const int i = 2 * k;
      const int mv = mbase[i * 64];         // early issue
      QK(scB, bO);                          // QK(e+1)
      storeKV(bN);                          // tile e+2 -> free buf
      if (i + 3 < 32) loadKV(i + 3);        // refill regs
      SOFTPV(scA, mv, bE + 8192);           // softmax(e); PV(e) from V HALF
      __syncthreads();
      char* tmp = bE; bE = bO; bO = bN; bN = tmp;
    }
    // step B: tile o = 2k+1
    {
      const int i = 2 * k + 1;
      const int mv = mbase[i * 64];
      QK(scA, bO);                          // QK(e+2)
      storeKV(bN);
      if (i + 3 < 32) loadKV(i + 3);
      SOFTPV(scB, mv, bE + 8192);
      __syncthreads();
      char* tmp = bE; bE = bO; bO = bN; bN = tmp;
    }
  }
  // epilogue: tiles 30, 31 (in bufs bE, bO; no more staging)
  {
    const int mv30 = mbase[30 * 64];
    const int mv31 = mbase[31 * 64];
    QK(scB, bO);                            // QK(31)
    SOFTPV(scA, mv30, bE + 8192);           // tile 30
    SOFTPV(scB, mv31, bO + 8192);           // tile 31
  }

  const float l_tot = l_run + __shfl_xor(l_run, 32, 64);
  const float inv_l = 1.0f / l_tot;
  unsigned short* cb = ctx + (size_t)qrow * 1024 + h * 64;
#pragma unroll
  for (int dt = 0; dt < 2; ++dt)
#pragma unroll
    for (int rq = 0; rq < 4; ++rq) {
      uint2 o;
      o.x = pk2bf(acc[dt][rq * 4 + 0] * inv_l, acc[dt][rq * 4 + 1] * inv_l);
      o.y = pk2bf(acc[dt][rq * 4 + 2] * inv_l, acc[dt][rq * 4 + 3] * inv_l);
      *(uint2*)(cb + dt * 32 + rq * 8 + hi * 4) = o;
    }
}

extern "C" void kernel_launch(void* const* d_in, const int* in_sizes, int n_in,
                              void* d_out, int out_size, void* d_ws, size_t ws_size,
                              hipStream_t stream) {
  const float* query = (const float*)d_in[0];
  const float* key = (const float*)d_in[1];
  const float* value = (const float*)d_in[2];
  const int* mask = (const int*)d_in[3];
  const float* Wq = (const float*)d_in[4];
  const float* bq = (const float*)d_in[5];
  const float* Wk = (const float*)d_in[6];
  const float* bk = (const float*)d_in[7];
  const float* Wv = (const float*)d_in[8];
  const float* bv = (const float*)d_in[9];
  const float* Wo = (const float*)d_in[10];
  const float* bo = (const float*)d_in[11];
  float* out = (float*)d_out;

  const size_t MB = 1024 * 1024;
  if (ws_size < 40 * MB) return;
  char* ws = (char*)d_ws;
  unsigned short* WqT = (unsigned short*)(ws);
  unsigned short* WkT = (unsigned short*)(ws + 2 * MB);
  unsigned short* WvT = (unsigned short*)(ws + 4 * MB);
  unsigned short* WoT = (unsigned short*)(ws + 6 * MB);
  unsigned short* Qb = (unsigned short*)(ws + 8 * MB);
  unsigned short* Kb = (unsigned short*)(ws + 16 * MB);
  unsigned short* Vt = (unsigned short*)(ws + 24 * MB);
  unsigned short* ctx = (unsigned short*)(ws + 32 * MB);

  const dim3 tb(256);
  const float qscale = 0.125f * 1.4426950408889634f;

  if (ws_size >= 64 * MB) {
    unsigned short* Qc = (unsigned short*)(ws + 40 * MB);
    unsigned short* Kc = (unsigned short*)(ws + 48 * MB);
    unsigned short* Vc = (unsigned short*)(ws + 56 * MB);
    prep_kernel<<<dim3(7168), tb, 0, stream>>>(Wq, Wk, Wv, Wo, WqT, WkT, WvT, WoT,
                                               query, key, value, Qc, Kc, Vc);
    qkv_gemm_bf16<<<dim3(8, 32, 3), tb, 0, stream>>>(Qc, Kc, Vc, WqT, WkT, WvT,
                                                     bq, bk, bv, Qb, Kb, Vt, qscale);
  } else {
    wt4_kernel<<<dim3(16, 16, 4), tb, 0, stream>>>(Wq, Wk, Wv, Wo, WqT, WkT, WvT, WoT);
    qkv_gemm_f32<<<dim3(8, 32, 3), tb, 0, stream>>>(query, key, value, WqT, WkT, WvT,
                                                    bq, bk, bv, Qb, Kb, Vt, qscale);
  }

  attn_kernel<<<dim3(16, 32), tb, 0, stream>>>(Qb, Kb, Vt, mask, ctx);

  out_gemm<<<dim3(16, 32), tb, 0, stream>>>(ctx, WoT, bo, out);
}

// Round 15
// 117.232 us; speedup vs baseline: 1.9207x; 1.0440x over previous
//
#include <hip/hip_runtime.h>
#include <hip/hip_bf16.h>
#include <stdint.h>

typedef short s16x8 __attribute__((ext_vector_type(8)));
typedef float f32x4 __attribute__((ext_vector_type(4)));
typedef float f32x16 __attribute__((ext_vector_type(16)));

union FragU { uint4 u; s16x8 v; };

static __device__ __forceinline__ uint32_t pk2bf(float a, float b) {
  union { __hip_bfloat162 h; uint32_t u; } cv;
  cv.h = __float22bfloat162_rn(make_float2(a, b));
  return cv.u;
}

static __device__ __forceinline__ unsigned short f2bf(float f) {
  union { float f; uint32_t u; } x; x.f = f;
  uint32_t r = x.u + 0x7FFFu + ((x.u >> 16) & 1u);  // RNE
  return (unsigned short)(r >> 16);
}

static __device__ __forceinline__ void gl_lds16(const void* g, void* lds_wave_base) {
  __builtin_amdgcn_global_load_lds(
      (const __attribute__((address_space(1))) uint32_t*)(uintptr_t)g,
      (__attribute__((address_space(3))) uint32_t*)(uintptr_t)lds_wave_base, 16, 0, 0);
}

// ---------------- prep: 4x weight transpose (blocks 0-1023) + qkv fp32->bf16 cvt ----------
__global__ __launch_bounds__(256) void prep_kernel(const float* __restrict__ W0,
                                                   const float* __restrict__ W1,
                                                   const float* __restrict__ W2,
                                                   const float* __restrict__ W3,
                                                   unsigned short* __restrict__ T0,
                                                   unsigned short* __restrict__ T1,
                                                   unsigned short* __restrict__ T2,
                                                   unsigned short* __restrict__ T3,
                                                   const float* __restrict__ qs,
                                                   const float* __restrict__ ks,
                                                   const float* __restrict__ vs,
                                                   unsigned short* __restrict__ Qc,
                                                   unsigned short* __restrict__ Kc,
                                                   unsigned short* __restrict__ Vc) {
  __shared__ unsigned short tile[64][68];
  const int blk = blockIdx.x;
  const int t = threadIdx.x;
  if (blk < 1024) {
    const int z = blk >> 8;
    const float* W = (z == 0) ? W0 : (z == 1) ? W1 : (z == 2) ? W2 : W3;
    unsigned short* WT = (z == 0) ? T0 : (z == 1) ? T1 : (z == 2) ? T2 : T3;
    const int n0 = (blk & 15) * 64, k0 = ((blk >> 4) & 15) * 64;
    const int r = t >> 4, c4 = (t & 15) * 4;
#pragma unroll
    for (int i = 0; i < 4; ++i) {
      const int k = i * 16 + r;
      const float4 v = *(const float4*)&W[(k0 + k) * 1024 + n0 + c4];
      tile[k][c4 + 0] = f2bf(v.x);
      tile[k][c4 + 1] = f2bf(v.y);
      tile[k][c4 + 2] = f2bf(v.z);
      tile[k][c4 + 3] = f2bf(v.w);
    }
    __syncthreads();
#pragma unroll
    for (int i = 0; i < 4; ++i) {
      const int n = i * 16 + r;
      ushort4 o;
      o.x = tile[c4 + 0][n];
      o.y = tile[c4 + 1][n];
      o.z = tile[c4 + 2][n];
      o.w = tile[c4 + 3][n];
      *(ushort4*)&WT[(n0 + n) * 1024 + k0 + c4] = o;
    }
  } else {
    const int c = blk - 1024;  // 0..6143
    const int z = c >> 11, sub = c & 2047;
    const float* src = (z == 0) ? qs : (z == 1) ? ks : vs;
    unsigned short* dst = (z == 0) ? Qc : (z == 1) ? Kc : Vc;
    const size_t base = ((size_t)sub * 256 + t) * 8;
    const float4 f0 = *(const float4*)(src + base);
    const float4 f1 = *(const float4*)(src + base + 4);
    const uint4 o{pk2bf(f0.x, f0.y), pk2bf(f0.z, f0.w), pk2bf(f1.x, f1.y), pk2bf(f1.z, f1.w)};
    *(uint4*)(dst + base) = o;
  }
}

// legacy wt-only (fallback path when ws too small for cvt buffers)
__global__ __launch_bounds__(256) void wt4_kernel(const float* __restrict__ W0,
                                                  const float* __restrict__ W1,
                                                  const float* __restrict__ W2,
                                                  const float* __restrict__ W3,
                                                  unsigned short* __restrict__ T0,
                                                  unsigned short* __restrict__ T1,
                                                  unsigned short* __restrict__ T2,
                                                  unsigned short* __restrict__ T3) {
  __shared__ unsigned short tile[64][68];
  const int z = blockIdx.z;
  const float* W = (z == 0) ? W0 : (z == 1) ? W1 : (z == 2) ? W2 : W3;
  unsigned short* WT = (z == 0) ? T0 : (z == 1) ? T1 : (z == 2) ? T2 : T3;
  const int t = threadIdx.x;
  const int n0 = blockIdx.x * 64, k0 = blockIdx.y * 64;
  const int r = t >> 4, c4 = (t & 15) * 4;
#pragma unroll
  for (int i = 0; i < 4; ++i) {
    const int k = i * 16 + r;
    const float4 v = *(const float4*)&W[(k0 + k) * 1024 + n0 + c4];
    tile[k][c4 + 0] = f2bf(v.x);
    tile[k][c4 + 1] = f2bf(v.y);
    tile[k][c4 + 2] = f2bf(v.z);
    tile[k][c4 + 3] = f2bf(v.w);
  }
  __syncthreads();
#pragma unroll
  for (int i = 0; i < 4; ++i) {
    const int n = i * 16 + r;
    ushort4 o;
    o.x = tile[c4 + 0][n];
    o.y = tile[c4 + 1][n];
    o.z = tile[c4 + 2][n];
    o.w = tile[c4 + 3][n];
    *(ushort4*)&WT[(n0 + n) * 1024 + k0 + c4] = o;
  }
}

// ---------------- fused QKV GEMM, all-bf16, 3-buf counted-vmcnt pipeline ----------------
__global__ __launch_bounds__(256, 3) void qkv_gemm_bf16(const unsigned short* __restrict__ Aq,
                                                        const unsigned short* __restrict__ Ak,
                                                        const unsigned short* __restrict__ Av,
                                                        const unsigned short* __restrict__ Wq,
                                                        const unsigned short* __restrict__ Wk,
                                                        const unsigned short* __restrict__ Wv,
                                                        const float* __restrict__ bq,
                                                        const float* __restrict__ bk,
                                                        const float* __restrict__ bv,
                                                        unsigned short* __restrict__ Qb,
                                                        unsigned short* __restrict__ Kb,
                                                        unsigned short* __restrict__ Vt,
                                                        const float qscale) {
  __shared__ char AsB[3][8192];
  __shared__ char BsB[3][8192];
  const int t = threadIdx.x;
  const int z = blockIdx.z;
  const unsigned short* A = (z == 0) ? Aq : (z == 1) ? Ak : Av;
  const unsigned short* BT = (z == 0) ? Wq : (z == 1) ? Wk : Wv;
  const float* bias = (z == 0) ? bq : (z == 1) ? bk : bv;
  const float scale = (z == 0) ? qscale : 1.0f;

  const int lane = t & 63, w = t >> 6;
  const int g = lane >> 4, li = lane & 15;
  const int wr = (w >> 1) * 64, wc = (w & 1) * 64;
  const int lin = blockIdx.x + 8 * blockIdx.y;
  const int work = (lin & 7) * 32 + (lin >> 3);
  const int m0 = (work >> 3) * 128, n0 = (work & 7) * 128;

  const int r1 = t >> 2, c1 = (t & 3) ^ ((r1 >> 1) & 3);
  const int r2 = r1 + 64, c2 = (t & 3) ^ ((r2 >> 1) & 3);

  auto stage = [&](int kt, int buf) {
    const int k0 = kt * 32;
    gl_lds16(A + (size_t)(m0 + r1) * 1024 + k0 + c1 * 8, &AsB[buf][0] + (w << 10));
    gl_lds16(A + (size_t)(m0 + r2) * 1024 + k0 + c2 * 8, &AsB[buf][0] + 4096 + (w << 10));
    gl_lds16(BT + (size_t)(n0 + r1) * 1024 + k0 + c1 * 8, &BsB[buf][0] + (w << 10));
    gl_lds16(BT + (size_t)(n0 + r2) * 1024 + k0 + c2 * 8, &BsB[buf][0] + 4096 + (w << 10));
  };

  f32x4 acc[4][4] = {};
  stage(0, 0);
  stage(1, 1);
  asm volatile("s_waitcnt vmcnt(4)" ::: "memory");
  asm volatile("s_barrier" ::: "memory");

  int cur = 0;
  for (int kt = 0; kt < 32; ++kt) {
    if (kt < 30) {
      int nb = cur + 2; if (nb >= 3) nb -= 3;
      stage(kt + 2, nb);
    }
    const char* Ab = &AsB[cur][0];
    const char* Bb = &BsB[cur][0];
    FragU a[4], bf[4];
#pragma unroll
    for (int i = 0; i < 4; ++i) {
      const int ra = wr + i * 16 + li;
      a[i].u = *(const uint4*)(Ab + ra * 64 + ((g ^ ((ra >> 1) & 3)) << 4));
      const int rb = wc + i * 16 + li;
      bf[i].u = *(const uint4*)(Bb + rb * 64 + ((g ^ ((rb >> 1) & 3)) << 4));
    }
#pragma unroll
    for (int fm = 0; fm < 4; ++fm)
#pragma unroll
      for (int fn = 0; fn < 4; ++fn)
        acc[fm][fn] = __builtin_amdgcn_mfma_f32_16x16x32_bf16(a[fm].v, bf[fn].v, acc[fm][fn], 0, 0, 0);

    if (kt < 30) {
      asm volatile("s_waitcnt vmcnt(4)" ::: "memory");
    } else if (kt == 30) {
      asm volatile("s_waitcnt vmcnt(0)" ::: "memory");
    }
    if (kt < 31) asm volatile("s_barrier" ::: "memory");
    cur = (cur == 2) ? 0 : cur + 1;
  }

  unsigned short* OutN = (z == 0) ? Qb : Kb;
#pragma unroll
  for (int fn = 0; fn < 4; ++fn) {
    const int n = n0 + wc + fn * 16 + li;
    const float bv2 = bias[n];
#pragma unroll
    for (int fm = 0; fm < 4; ++fm) {
      const int mb = m0 + wr + fm * 16 + g * 4;
      const f32x4 v = acc[fm][fn];
      ushort4 pk;
      pk.x = f2bf((v[0] + bv2) * scale);
      pk.y = f2bf((v[1] + bv2) * scale);
      pk.z = f2bf((v[2] + bv2) * scale);
      pk.w = f2bf((v[3] + bv2) * scale);
      if (z == 2) {
        const int bb = mb >> 11, s = mb & 2047;
        *(ushort4*)&Vt[(size_t)(bb * 1024 + n) * 2048 + s] = pk;
      } else {
        unsigned short* o = OutN;
        o[(size_t)(mb + 0) * 1024 + n] = pk.x;
        o[(size_t)(mb + 1) * 1024 + n] = pk.y;
        o[(size_t)(mb + 2) * 1024 + n] = pk.z;
        o[(size_t)(mb + 3) * 1024 + n] = pk.w;
      }
    }
  }
}

// ---------------- fallback fused QKV GEMM (fp32 A reg-convert, 2-buf) -------------------
__global__ __launch_bounds__(256, 3) void qkv_gemm_f32(const float* __restrict__ Aq,
                                                       const float* __restrict__ Ak,
                                                       const float* __restrict__ Av,
                                                       const unsigned short* __restrict__ Wq,
                                                       const unsigned short* __restrict__ Wk,
                                                       const unsigned short* __restrict__ Wv,
                                                       const float* __restrict__ bq,
                                                       const float* __restrict__ bk,
                                                       const float* __restrict__ bv,
                                                       unsigned short* __restrict__ Qb,
                                                       unsigned short* __restrict__ Kb,
                                                       unsigned short* __restrict__ Vt,
                                                       const float qscale) {
  __shared__ unsigned short As[2][128 * 32];
  __shared__ unsigned short Bs[2][128 * 32];
  const int t = threadIdx.x;
  const int z = blockIdx.z;
  const float* A = (z == 0) ? Aq : (z == 1) ? Ak : Av;
  const unsigned short* BT = (z == 0) ? Wq : (z == 1) ? Wk : Wv;
  const float* bias = (z == 0) ? bq : (z == 1) ? bk : bv;
  const float scale = (z == 0) ? qscale : 1.0f;

  const int lane = t & 63, w = t >> 6;
  const int g = lane >> 4, li = lane & 15;
  const int wr = (w >> 1) * 64, wc = (w & 1) * 64;
  const int lin = blockIdx.x + 8 * blockIdx.y;
  const int work = (lin & 7) * 32 + (lin >> 3);
  const int m0 = (work >> 3) * 128, n0 = (work & 7) * 128;

  const int arow = t >> 1, ac0 = (t & 1) * 2, asw = (arow >> 1) & 3;
  const int br1 = t >> 2, bg1 = (t & 3) ^ ((br1 >> 1) & 3);
  const int br2 = br1 + 64, bg2 = (t & 3) ^ ((br2 >> 1) & 3);

  auto stageB = [&](int k0, int buf) {
    gl_lds16(BT + (size_t)(n0 + br1) * 1024 + k0 + bg1 * 8, (char*)&Bs[buf][0] + (w << 10));
    gl_lds16(BT + (size_t)(n0 + br2) * 1024 + k0 + bg2 * 8, (char*)&Bs[buf][0] + 4096 + (w << 10));
  };

  uint4 ar0, ar1;
  auto loadA = [&](int k0) {
    const float* ga = A + (size_t)(m0 + arow) * 1024 + k0 + ac0 * 8;
    const float4 f0 = *(const float4*)(ga + 0), f1 = *(const float4*)(ga + 4);
    const float4 f2 = *(const float4*)(ga + 8), f3 = *(const float4*)(ga + 12);
    ar0 = uint4{pk2bf(f0.x, f0.y), pk2bf(f0.z, f0.w), pk2bf(f1.x, f1.y), pk2bf(f1.z, f1.w)};
    ar1 = uint4{pk2bf(f2.x, f2.y), pk2bf(f2.z, f2.w), pk2bf(f3.x, f3.y), pk2bf(f3.z, f3.w)};
  };
  auto storeA = [&](int buf) {
    char* ab = (char*)&As[buf][0] + arow * 64;
    *(uint4*)(ab + ((ac0 ^ asw) << 4)) = ar0;
    *(uint4*)(ab + (((ac0 + 1) ^ asw) << 4)) = ar1;
  };

  f32x4 acc[4][4] = {};
  stageB(0, 0);
  loadA(0);
  storeA(0);
  __syncthreads();
  int cur = 0;
  for (int k0 = 0; k0 < 1024; k0 += 32) {
    const bool more = (k0 + 32) < 1024;
    if (more) {
      stageB(k0 + 32, cur ^ 1);
      loadA(k0 + 32);
    }
    const char* Ab = (const char*)&As[cur][0];
    const char* Bb = (const char*)&Bs[cur][0];
    FragU a[4], bf[4];
#pragma unroll
    for (int i = 0; i < 4; ++i) {
      const int rowa = wr + i * 16 + li;
      a[i].u = *(const uint4*)(Ab + rowa * 64 + (((g) ^ ((rowa >> 1) & 3)) << 4));
      const int rowb = wc + i * 16 + li;
      bf[i].u = *(const uint4*)(Bb + rowb * 64 + (((g) ^ ((rowb >> 1) & 3)) << 4));
    }
#pragma unroll
    for (int fm = 0; fm < 4; ++fm)
#pragma unroll
      for (int fn = 0; fn < 4; ++fn)
        acc[fm][fn] = __builtin_amdgcn_mfma_f32_16x16x32_bf16(a[fm].v, bf[fn].v, acc[fm][fn], 0, 0, 0);
    if (more) storeA(cur ^ 1);
    __syncthreads();
    cur ^= 1;
  }

  unsigned short* OutN = (z == 0) ? Qb : Kb;
#pragma unroll
  for (int fn = 0; fn < 4; ++fn) {
    const int n = n0 + wc + fn * 16 + li;
    const float bv2 = bias[n];
#pragma unroll
    for (int fm = 0; fm < 4; ++fm) {
      const int mb = m0 + wr + fm * 16 + g * 4;
      const f32x4 v = acc[fm][fn];
      ushort4 pk;
      pk.x = f2bf((v[0] + bv2) * scale);
      pk.y = f2bf((v[1] + bv2) * scale);
      pk.z = f2bf((v[2] + bv2) * scale);
      pk.w = f2bf((v[3] + bv2) * scale);
      if (z == 2) {
        const int bb = mb >> 11, s = mb & 2047;
        *(ushort4*)&Vt[(size_t)(bb * 1024 + n) * 2048 + s] = pk;
      } else {
        unsigned short* o = OutN;
        o[(size_t)(mb + 0) * 1024 + n] = pk.x;
        o[(size_t)(mb + 1) * 1024 + n] = pk.y;
        o[(size_t)(mb + 2) * 1024 + n] = pk.z;
        o[(size_t)(mb + 3) * 1024 + n] = pk.w;
      }
    }
  }
}

// ---------------- out GEMM: fp32 out = ctx(bf16) @ WoT^T + bo ----------------
// BM=128, BN=64 -> 512 blocks (2/CU). 3-buf counted vmcnt(3). 4 waves (2m x 2n), 4x2 frags.
__global__ __launch_bounds__(256, 3) void out_gemm(const unsigned short* __restrict__ A,
                                                   const unsigned short* __restrict__ BT,
                                                   const float* __restrict__ bias,
                                                   float* __restrict__ Out) {
  __shared__ char AsB[3][8192];
  __shared__ char BsB[3][4096];
  const int t = threadIdx.x;
  const int lane = t & 63, w = t >> 6;
  const int g = lane >> 4, li = lane & 15;
  const int wr = (w >> 1) * 64, wc = (w & 1) * 32;
  const int lin = blockIdx.x + 16 * blockIdx.y;        // grid (16,32) = 512
  const int work = (lin & 7) * 64 + (lin >> 3);        // XCD-contiguous
  const int m0 = (work >> 4) * 128, n0 = (work & 15) * 64;

  const int r1 = t >> 2, c1 = (t & 3) ^ ((r1 >> 1) & 3);
  const int r2 = r1 + 64, c2 = (t & 3) ^ ((r2 >> 1) & 3);

  auto stage = [&](int kt, int buf) {
    const int k0 = kt * 32;
    gl_lds16(A + (size_t)(m0 + r1) * 1024 + k0 + c1 * 8, &AsB[buf][0] + (w << 10));
    gl_lds16(A + (size_t)(m0 + r2) * 1024 + k0 + c2 * 8, &AsB[buf][0] + 4096 + (w << 10));
    gl_lds16(BT + (size_t)(n0 + r1) * 1024 + k0 + c1 * 8, &BsB[buf][0] + (w << 10));
  };

  f32x4 acc[4][2] = {};
  stage(0, 0);
  stage(1, 1);
  asm volatile("s_waitcnt vmcnt(3)" ::: "memory");
  asm volatile("s_barrier" ::: "memory");

  int cur = 0;
  for (int kt = 0; kt < 32; ++kt) {
    if (kt < 30) {
      int nb = cur + 2; if (nb >= 3) nb -= 3;
      stage(kt + 2, nb);
    }
    const char* Ab = &AsB[cur][0];
    const char* Bb = &BsB[cur][0];
    FragU a[4], bf[2];
#pragma unroll
    for (int i = 0; i < 4; ++i) {
      const int ra = wr + i * 16 + li;
      a[i].u = *(const uint4*)(Ab + ra * 64 + ((g ^ ((ra >> 1) & 3)) << 4));
    }
#pragma unroll
    for (int j = 0; j < 2; ++j) {
      const int rb = wc + j * 16 + li;
      bf[j].u = *(const uint4*)(Bb + rb * 64 + ((g ^ ((rb >> 1) & 3)) << 4));
    }
#pragma unroll
    for (int fm = 0; fm < 4; ++fm)
#pragma unroll
      for (int fn = 0; fn < 2; ++fn)
        acc[fm][fn] = __builtin_amdgcn_mfma_f32_16x16x32_bf16(a[fm].v, bf[fn].v, acc[fm][fn], 0, 0, 0);

    if (kt < 30) {
      asm volatile("s_waitcnt vmcnt(3)" ::: "memory");
    } else if (kt == 30) {
      asm volatile("s_waitcnt vmcnt(0)" ::: "memory");
    }
    if (kt < 31) asm volatile("s_barrier" ::: "memory");
    cur = (cur == 2) ? 0 : cur + 1;
  }

#pragma unroll
  for (int fn = 0; fn < 2; ++fn) {
    const int n = n0 + wc + fn * 16 + li;
    const float bv = bias[n];
#pragma unroll
    for (int fm = 0; fm < 4; ++fm) {
      const int mb = m0 + wr + fm * 16 + g * 4;
      const f32x4 v = acc[fm][fn];
#pragma unroll
      for (int r = 0; r < 4; ++r) Out[(size_t)(mb + r) * 1024 + n] = v[r] + bv;
    }
  }
}

// ---------------- flash attention, 32x32 swapped structure (R9-exact, best measured) -----
// 512 blocks (XCD-swizzled), 4 waves x 32 q-rows, KV tile 64. Reg-staged dbuf K/V,
// one __syncthreads per tile, setprio around MFMA, softmax log2-domain, m_run init 8.
__global__ __launch_bounds__(256, 2) void attn_kernel(const unsigned short* __restrict__ Qb,
                                                      const unsigned short* __restrict__ Kb,
                                                      const unsigned short* __restrict__ Vt,
                                                      const int* __restrict__ mask,
                                                      unsigned short* __restrict__ ctx) {
  __shared__ unsigned short Ks[2][64 * 64];  // [kv][d], byte ^= (kv&7)<<4
  __shared__ unsigned short Vs[2][64 * 64];  // [d][kv], byte ^= (d&7)<<4
  const int t = threadIdx.x, lane = t & 63, w = t >> 6;
  const int l31 = lane & 31, hi = lane >> 5;
  const int d0 = blockIdx.x + 16 * blockIdx.y;
  const int work = (d0 & 7) * 64 + (d0 >> 3);
  const int qblk = work & 15, bh = work >> 4;
  const int b = bh >> 4, h = bh & 15;
  const int q0 = qblk * 128;
  const int qrow = b * 2048 + q0 + w * 32 + l31;

  const int srow = t >> 3, sch = t & 7;

  uint4 kr0, kr1, vr0, vr1;
  int mv = 1;
  auto loadKV = [&](int kvn) {
    const unsigned short* kbase = Kb + (size_t)(b * 2048 + kvn) * 1024 + h * 64;
    kr0 = *(const uint4*)(kbase + (size_t)srow * 1024 + sch * 8);
    kr1 = *(const uint4*)(kbase + (size_t)(srow + 32) * 1024 + sch * 8);
    const unsigned short* vbase = Vt + (size_t)(b * 1024 + h * 64) * 2048 + kvn;
    vr0 = *(const uint4*)(vbase + (size_t)srow * 2048 + sch * 8);
    vr1 = *(const uint4*)(vbase + (size_t)(srow + 32) * 2048 + sch * 8);
    mv = mask[b * 2048 + kvn + lane];
  };
  auto storeKV = [&](int buf) {
    char* kb = (char*)&Ks[buf][0];
    char* vb = (char*)&Vs[buf][0];
    const int o0 = srow * 128 + ((sch * 16) ^ ((srow & 7) << 4));
    const int o1 = (srow + 32) * 128 + ((sch * 16) ^ ((srow & 7) << 4));
    *(uint4*)(kb + o0) = kr0;
    *(uint4*)(kb + o1) = kr1;
    *(uint4*)(vb + o0) = vr0;
    *(uint4*)(vb + o1) = vr1;
  };

  FragU qf[4];
  {
    const unsigned short* qb = Qb + (size_t)qrow * 1024 + h * 64 + hi * 8;
#pragma unroll
    for (int dc = 0; dc < 4; ++dc) qf[dc].u = *(const uint4*)(qb + dc * 16);
  }

  loadKV(0);
  storeKV(0);
  __syncthreads();

  f32x16 acc[2] = {};
  float m_run = 8.0f, l_run = 0.f;
  int cur = 0;

  for (int tile = 0; tile < 32; ++tile) {
    const bool more = tile + 1 < 32;
    const int mvcur = mv;
    if (more) loadKV((tile + 1) * 64);

    f32x16 sc[2] = {};
    {
      const char* kb = (const char*)&Ks[cur][0];
      __builtin_amdgcn_s_setprio(1);
#pragma unroll
      for (int t2 = 0; t2 < 2; ++t2) {
        const int row = t2 * 32 + l31;
        const int sw = (row & 7) << 4;
        const int rb = row * 128;
#pragma unroll
        for (int dc = 0; dc < 4; ++dc) {
          FragU kf;
          kf.u = *(const uint4*)(kb + rb + ((16 * (dc * 2 + hi)) ^ sw));
          sc[t2] = __builtin_amdgcn_mfma_f32_32x32x16_bf16(kf.v, qf[dc].v, sc[t2], 0, 0, 0);
        }
      }
      __builtin_amdgcn_s_setprio(0);
    }

    if (!__all(mvcur != 0)) {
#pragma unroll
      for (int t2 = 0; t2 < 2; ++t2)
#pragma unroll
        for (int r = 0; r < 16; ++r) {
          const int kvv = t2 * 32 + (r & 3) + 8 * (r >> 2) + 4 * hi;
          sc[t2][r] += (__shfl(mvcur, kvv, 64) ? 0.f : -30000.f);
        }
    }

    float pm = sc[0][0];
#pragma unroll
    for (int t2 = 0; t2 < 2; ++t2)
#pragma unroll
      for (int r = 0; r < 16; ++r) pm = fmaxf(pm, sc[t2][r]);
    pm = fmaxf(pm, __shfl_xor(pm, 32, 64));

    if (!__all(pm <= m_run + 8.f)) {
      const float m_new = fmaxf(m_run, pm);
      const float rsc = __builtin_amdgcn_exp2f(m_run - m_new);
      m_run = m_new;
      l_run *= rsc;
#pragma unroll
      for (int dt = 0; dt < 2; ++dt)
#pragma unroll
        for (int r = 0; r < 16; ++r) acc[dt][r] *= rsc;
    }

    float rs = 0.f;
#pragma unroll
    for (int t2 = 0; t2 < 2; ++t2)
#pragma unroll
      for (int r = 0; r < 16; ++r) {
        const float e = __builtin_amdgcn_exp2f(sc[t2][r] - m_run);
        sc[t2][r] = e;
        rs += e;
      }
    l_run += rs;

    FragU pf[4];
#pragma unroll
    for (int ks = 0; ks < 4; ++ks) {
      const int t2 = ks >> 1, s8 = (ks & 1) * 8;
      uint32_t U = pk2bf(sc[t2][s8 + 0], sc[t2][s8 + 1]);
      uint32_t V2 = pk2bf(sc[t2][s8 + 2], sc[t2][s8 + 3]);
      uint32_t X = pk2bf(sc[t2][s8 + 4], sc[t2][s8 + 5]);
      uint32_t Y = pk2bf(sc[t2][s8 + 6], sc[t2][s8 + 7]);
      asm("v_permlane32_swap_b32 %0, %1" : "+v"(U), "+v"(X));
      asm("v_permlane32_swap_b32 %0, %1" : "+v"(V2), "+v"(Y));
      pf[ks].u = uint4{U, V2, X, Y};
    }

    {
      const char* vb = (const char*)&Vs[cur][0];
      __builtin_amdgcn_s_setprio(1);
#pragma unroll
      for (int dt = 0; dt < 2; ++dt) {
        const int drow = dt * 32 + l31;
        const int sw = (drow & 7) << 4;
        const int rb = drow * 128;
#pragma unroll
        for (int ks = 0; ks < 4; ++ks) {
          FragU vf;
          vf.u = *(const uint4*)(vb + rb + ((16 * (ks * 2 + hi)) ^ sw));
          acc[dt] = __builtin_amdgcn_mfma_f32_32x32x16_bf16(vf.v, pf[ks].v, acc[dt], 0, 0, 0);
        }
      }
      __builtin_amdgcn_s_setprio(0);
    }

    if (more) storeKV(cur ^ 1);
    __syncthreads();
    cur ^= 1;
  }

  const float l_tot = l_run + __shfl_xor(l_run, 32, 64);
  const float inv_l = 1.0f / l_tot;
  unsigned short* cb = ctx + (size_t)qrow * 1024 + h * 64;
#pragma unroll
  for (int dt = 0; dt < 2; ++dt)
#pragma unroll
    for (int rq = 0; rq < 4; ++rq) {
      uint2 o;
      o.x = pk2bf(acc[dt][rq * 4 + 0] * inv_l, acc[dt][rq * 4 + 1] * inv_l);
      o.y = pk2bf(acc[dt][rq * 4 + 2] * inv_l, acc[dt][rq * 4 + 3] * inv_l);
      *(uint2*)(cb + dt * 32 + rq * 8 + hi * 4) = o;
    }
}

extern "C" void kernel_launch(void* const* d_in, const int* in_sizes, int n_in,
                              void* d_out, int out_size, void* d_ws, size_t ws_size,
                              hipStream_t stream) {
  const float* query = (const float*)d_in[0];
  const float* key = (const float*)d_in[1];
  const float* value = (const float*)d_in[2];
  const int* mask = (const int*)d_in[3];
  const float* Wq = (const float*)d_in[4];
  const float* bq = (const float*)d_in[5];
  const float* Wk = (const float*)d_in[6];
  const float* bk = (const float*)d_in[7];
  const float* Wv = (const float*)d_in[8];
  const float* bv = (const float*)d_in[9];
  const float* Wo = (const float*)d_in[10];
  const float* bo = (const float*)d_in[11];
  float* out = (float*)d_out;

  const size_t MB = 1024 * 1024;
  if (ws_size < 40 * MB) return;
  char* ws = (char*)d_ws;
  unsigned short* WqT = (unsigned short*)(ws);
  unsigned short* WkT = (unsigned short*)(ws + 2 * MB);
  unsigned short* WvT = (unsigned short*)(ws + 4 * MB);
  unsigned short* WoT = (unsigned short*)(ws + 6 * MB);
  unsigned short* Qb = (unsigned short*)(ws + 8 * MB);
  unsigned short* Kb = (unsigned short*)(ws + 16 * MB);
  unsigned short* Vt = (unsigned short*)(ws + 24 * MB);
  unsigned short* ctx = (unsigned short*)(ws + 32 * MB);

  const dim3 tb(256);
  const float qscale = 0.125f * 1.4426950408889634f;

  if (ws_size >= 64 * MB) {
    unsigned short* Qc = (unsigned short*)(ws + 40 * MB);
    unsigned short* Kc = (unsigned short*)(ws + 48 * MB);
    unsigned short* Vc = (unsigned short*)(ws + 56 * MB);
    prep_kernel<<<dim3(7168), tb, 0, stream>>>(Wq, Wk, Wv, Wo, WqT, WkT, WvT, WoT,
                                               query, key, value, Qc, Kc, Vc);
    qkv_gemm_bf16<<<dim3(8, 32, 3), tb, 0, stream>>>(Qc, Kc, Vc, WqT, WkT, WvT,
                                                     bq, bk, bv, Qb, Kb, Vt, qscale);
  } else {
    wt4_kernel<<<dim3(16, 16, 4), tb, 0, stream>>>(Wq, Wk, Wv, Wo, WqT, WkT, WvT, WoT);
    qkv_gemm_f32<<<dim3(8, 32, 3), tb, 0, stream>>>(query, key, value, WqT, WkT, WvT,
                                                    bq, bk, bv, Qb, Kb, Vt, qscale);
  }

  attn_kernel<<<dim3(16, 32), tb, 0, stream>>>(Qb, Kb, Vt, mask, ctx);

  out_gemm<<<dim3(16, 32), tb, 0, stream>>>(ctx, WoT, bo, out);
}